// Round 1
// baseline (27301.221 us; speedup 1.0000x reference)
//
#include <hip/hip_runtime.h>
#include <math.h>

#define B_    32
#define SEQ_  197
#define DIM_  768
#define HEADS_ 12
#define HD_   64
#define MLP_  3072
#define NCLS_ 1000
#define DEPTH_ 12

#define BM 128
#define BN 64
#define BK 16

enum { EPI_BIAS = 0, EPI_BIAS_RES = 1, EPI_GELU = 2, EPI_QKV = 3 };

// C[m][n] = sum_k A[m][k] * W[n][k] (+ bias[n]) with epilogue variants.
// A: [M][K] row-major, W: [N][K] row-major.
template <int EPI>
__launch_bounds__(256)
__global__ void gemm_nt(const float* __restrict__ A, const float* __restrict__ W,
                        const float* __restrict__ bias, float* __restrict__ C,
                        int M, int N, int K,
                        float* __restrict__ qo, float* __restrict__ ko, float* __restrict__ vo) {
    __shared__ __align__(16) float As[BK][BM + 4];  // [k][m], ld=132 (528B, 16B-mult)
    __shared__ __align__(16) float Ws[BK][BN + 4];  // [k][n], ld=68  (272B, 16B-mult)
    const int tid = threadIdx.x;
    const int tx = tid & 15, ty = tid >> 4;
    const int m0 = blockIdx.y * BM;
    const int n0 = blockIdx.x * BN;

    float acc[8][4];
#pragma unroll
    for (int i = 0; i < 8; i++)
#pragma unroll
        for (int j = 0; j < 4; j++) acc[i][j] = 0.f;

    for (int k0 = 0; k0 < K; k0 += BK) {
        // A tile: 128x16 = 512 float4, 2 per thread
#pragma unroll
        for (int it = 0; it < 2; it++) {
            int e4 = tid + it * 256;
            int ml = e4 >> 2;
            int kl = (e4 & 3) * 4;
            int m = m0 + ml;
            float4 val = make_float4(0.f, 0.f, 0.f, 0.f);
            if (m < M) val = *(const float4*)&A[(size_t)m * K + k0 + kl];
            As[kl + 0][ml] = val.x; As[kl + 1][ml] = val.y;
            As[kl + 2][ml] = val.z; As[kl + 3][ml] = val.w;
        }
        // W tile: 64x16 = 256 float4, 1 per thread
        {
            int nl = tid >> 2;
            int kl = (tid & 3) * 4;
            int n = n0 + nl;
            float4 val = make_float4(0.f, 0.f, 0.f, 0.f);
            if (n < N) val = *(const float4*)&W[(size_t)n * K + k0 + kl];
            Ws[kl + 0][nl] = val.x; Ws[kl + 1][nl] = val.y;
            Ws[kl + 2][nl] = val.z; Ws[kl + 3][nl] = val.w;
        }
        __syncthreads();
#pragma unroll
        for (int kk = 0; kk < BK; kk++) {
            float4 a0 = *(const float4*)&As[kk][ty * 8];
            float4 a1 = *(const float4*)&As[kk][ty * 8 + 4];
            float4 w0 = *(const float4*)&Ws[kk][tx * 4];
            float av[8] = {a0.x, a0.y, a0.z, a0.w, a1.x, a1.y, a1.z, a1.w};
            float wv[4] = {w0.x, w0.y, w0.z, w0.w};
#pragma unroll
            for (int i = 0; i < 8; i++)
#pragma unroll
                for (int j = 0; j < 4; j++) acc[i][j] += av[i] * wv[j];
        }
        __syncthreads();
    }

#pragma unroll
    for (int i = 0; i < 8; i++) {
        int m = m0 + ty * 8 + i;
        if (m >= M) continue;
#pragma unroll
        for (int j = 0; j < 4; j++) {
            int n = n0 + tx * 4 + j;
            if (n >= N) continue;
            float val = acc[i][j] + bias[n];
            if constexpr (EPI == EPI_BIAS) {
                C[(size_t)m * N + n] = val;
            } else if constexpr (EPI == EPI_BIAS_RES) {
                C[(size_t)m * N + n] += val;  // C pre-holds residual x
            } else if constexpr (EPI == EPI_GELU) {
                C[(size_t)m * N + n] = 0.5f * val * (1.f + erff(val * 0.70710678118654752f));
            } else {  // EPI_QKV: scatter into q/k/v [B][HEADS][SEQ][HD]
                int b = m / SEQ_, s = m - b * SEQ_;
                int i3 = n / DIM_;
                int rem = n - i3 * DIM_;
                int hh = rem >> 6, d = rem & 63;
                float* dst = (i3 == 0) ? qo : (i3 == 1) ? ko : vo;
                dst[(((size_t)b * HEADS_ + hh) * SEQ_ + s) * HD_ + d] = val;
            }
        }
    }
}

// Patch embedding as gathered GEMM: M=6272 (b,gh,gw), N=768, K=768 (c,p,q).
__launch_bounds__(256)
__global__ void patch_embed(const float* __restrict__ img, const float* __restrict__ cw,
                            const float* __restrict__ cb, const float* __restrict__ pos,
                            float* __restrict__ x) {
    __shared__ __align__(16) float As[BK][BM + 4];
    __shared__ __align__(16) float Ws[BK][BN + 4];
    const int tid = threadIdx.x;
    const int tx = tid & 15, ty = tid >> 4;
    const int m0 = blockIdx.y * BM;  // grid.y = 49 exact
    const int n0 = blockIdx.x * BN;  // grid.x = 12 exact

    float acc[8][4];
#pragma unroll
    for (int i = 0; i < 8; i++)
#pragma unroll
        for (int j = 0; j < 4; j++) acc[i][j] = 0.f;

    for (int k0 = 0; k0 < 768; k0 += BK) {
#pragma unroll
        for (int it = 0; it < 2; it++) {
            int e4 = tid + it * 256;
            int ml = e4 >> 2;
            int kl = (e4 & 3) * 4;
            int m = m0 + ml;                 // < 6272 always
            int b = m / 196, pp = m - b * 196;
            int gh = pp / 14, gw = pp - gh * 14;
            int k = k0 + kl;
            int c = k >> 8, r = (k >> 4) & 15, qq = k & 15;
            const float* src =
                &img[(((size_t)(b * 3 + c) * 224) + gh * 16 + r) * 224 + gw * 16 + qq];
            float4 val = *(const float4*)src;  // qq multiple of 4 -> aligned
            As[kl + 0][ml] = val.x; As[kl + 1][ml] = val.y;
            As[kl + 2][ml] = val.z; As[kl + 3][ml] = val.w;
        }
        {
            int nl = tid >> 2;
            int kl = (tid & 3) * 4;
            float4 val = *(const float4*)&cw[(size_t)(n0 + nl) * 768 + k0 + kl];
            Ws[kl + 0][nl] = val.x; Ws[kl + 1][nl] = val.y;
            Ws[kl + 2][nl] = val.z; Ws[kl + 3][nl] = val.w;
        }
        __syncthreads();
#pragma unroll
        for (int kk = 0; kk < BK; kk++) {
            float4 a0 = *(const float4*)&As[kk][ty * 8];
            float4 a1 = *(const float4*)&As[kk][ty * 8 + 4];
            float4 w0 = *(const float4*)&Ws[kk][tx * 4];
            float av[8] = {a0.x, a0.y, a0.z, a0.w, a1.x, a1.y, a1.z, a1.w};
            float wv[4] = {w0.x, w0.y, w0.z, w0.w};
#pragma unroll
            for (int i = 0; i < 8; i++)
#pragma unroll
                for (int j = 0; j < 4; j++) acc[i][j] += av[i] * wv[j];
        }
        __syncthreads();
    }

#pragma unroll
    for (int i = 0; i < 8; i++) {
        int m = m0 + ty * 8 + i;
        int b = m / 196, pp = m - b * 196;
        size_t row = (size_t)b * SEQ_ + 1 + pp;
#pragma unroll
        for (int j = 0; j < 4; j++) {
            int n = n0 + tx * 4 + j;
            x[row * DIM_ + n] = acc[i][j] + cb[n] + pos[(size_t)(1 + pp) * DIM_ + n];
        }
    }
}

__global__ void cls_init(const float* __restrict__ cls, const float* __restrict__ pos,
                         float* __restrict__ x) {
    int idx = blockIdx.x * 256 + threadIdx.x;
    if (idx >= B_ * DIM_) return;
    int b = idx / DIM_, d = idx - b * DIM_;
    x[(size_t)b * SEQ_ * DIM_ + d] = cls[d] + pos[d];
}

// One block per row; 768 = 256*3. row_mul: input row = blockIdx.x*row_mul (final LN
// picks the CLS row b*197); output row = blockIdx.x.
__launch_bounds__(256)
__global__ void layernorm(const float* __restrict__ in, const float* __restrict__ g,
                          const float* __restrict__ bta, float* __restrict__ out, int row_mul) {
    const float* xr = in + (size_t)blockIdx.x * row_mul * DIM_;
    float* orow = out + (size_t)blockIdx.x * DIM_;
    int tid = threadIdx.x;
    float v0 = xr[tid], v1 = xr[tid + 256], v2 = xr[tid + 512];
    __shared__ float s1[256], s2[256];
    s1[tid] = v0 + v1 + v2;
    s2[tid] = v0 * v0 + v1 * v1 + v2 * v2;
    __syncthreads();
    for (int off = 128; off > 0; off >>= 1) {
        if (tid < off) { s1[tid] += s1[tid + off]; s2[tid] += s2[tid + off]; }
        __syncthreads();
    }
    float mean = s1[0] * (1.f / 768.f);
    float var = s2[0] * (1.f / 768.f) - mean * mean;
    float rstd = rsqrtf(var + 1e-6f);
    orow[tid]       = (v0 - mean) * rstd * g[tid] + bta[tid];
    orow[tid + 256] = (v1 - mean) * rstd * g[tid + 256] + bta[tid + 256];
    orow[tid + 512] = (v2 - mean) * rstd * g[tid + 512] + bta[tid + 512];
}

// One block per (b, head). K transposed in LDS; V streamed from L2.
__launch_bounds__(256)
__global__ void attention(const float* __restrict__ q, const float* __restrict__ k,
                          const float* __restrict__ v, float* __restrict__ o) {
    __shared__ __align__(16) float kT[64 * 200];   // [d][t], ld=200
    __shared__ __align__(16) float pbuf[4][200];
    __shared__ float qbuf[4][64];
    int bh = blockIdx.x;
    const float* qp = q + (size_t)bh * SEQ_ * HD_;
    const float* kp = k + (size_t)bh * SEQ_ * HD_;
    const float* vp = v + (size_t)bh * SEQ_ * HD_;
    int b = bh / HEADS_, hh = bh - b * HEADS_;
    float* op = o + (size_t)b * SEQ_ * DIM_ + hh * HD_;
    int tid = threadIdx.x;
    for (int e = tid; e < SEQ_ * HD_; e += 256) {
        int t = e >> 6, d = e & 63;
        kT[d * 200 + t] = kp[e];
    }
    __syncthreads();
    int w = tid >> 6, lane = tid & 63;
    int t0 = lane * 4;
    for (int s = w; s < SEQ_; s += 4) {
        qbuf[w][lane] = qp[s * HD_ + lane];
        float sc[4] = {0.f, 0.f, 0.f, 0.f};
        if (t0 < 200) {  // lane < 50
            for (int d = 0; d < 64; d++) {
                float qd = qbuf[w][d];
                float4 kv = *(const float4*)&kT[d * 200 + t0];
                sc[0] += qd * kv.x; sc[1] += qd * kv.y;
                sc[2] += qd * kv.z; sc[3] += qd * kv.w;
            }
        }
#pragma unroll
        for (int i = 0; i < 4; i++) {
            sc[i] *= 0.125f;  // 1/sqrt(64)
            if (t0 + i >= SEQ_) sc[i] = -INFINITY;
        }
        float mx = fmaxf(fmaxf(sc[0], sc[1]), fmaxf(sc[2], sc[3]));
        for (int off = 32; off; off >>= 1) mx = fmaxf(mx, __shfl_xor(mx, off));
        float e0 = expf(sc[0] - mx), e1 = expf(sc[1] - mx);
        float e2 = expf(sc[2] - mx), e3 = expf(sc[3] - mx);
        float sum = e0 + e1 + e2 + e3;
        for (int off = 32; off; off >>= 1) sum += __shfl_xor(sum, off);
        float inv = 1.f / sum;
        if (t0 < 200) {
            float4 pv = make_float4(e0 * inv, e1 * inv, e2 * inv, e3 * inv);
            *(float4*)&pbuf[w][t0] = pv;
        }
        // pbuf[w]/qbuf[w] produced and consumed by the same wave: no barrier needed.
        float oacc = 0.f;
#pragma unroll 4
        for (int t = 0; t < SEQ_; t++) oacc += pbuf[w][t] * vp[t * HD_ + lane];
        op[(size_t)s * DIM_ + lane] = oacc;
    }
}

extern "C" void kernel_launch(void* const* d_in, const int* in_sizes, int n_in,
                              void* d_out, int out_size, void* d_ws, size_t ws_size,
                              hipStream_t stream) {
    const float* img      = (const float*)d_in[0];
    const float* conv_w   = (const float*)d_in[1];
    const float* conv_b   = (const float*)d_in[2];
    const float* cls_tok  = (const float*)d_in[3];
    const float* pos_emb  = (const float*)d_in[4];
    const float* ln1_g    = (const float*)d_in[5];
    const float* ln1_b    = (const float*)d_in[6];
    const float* qkv_w    = (const float*)d_in[7];
    const float* qkv_b    = (const float*)d_in[8];
    const float* out_w    = (const float*)d_in[9];
    const float* out_b    = (const float*)d_in[10];
    const float* ln2_g    = (const float*)d_in[11];
    const float* ln2_b    = (const float*)d_in[12];
    const float* mlp_w1   = (const float*)d_in[13];
    const float* mlp_b1   = (const float*)d_in[14];
    const float* mlp_w2   = (const float*)d_in[15];
    const float* mlp_b2   = (const float*)d_in[16];
    const float* lnf_g    = (const float*)d_in[17];
    const float* lnf_b    = (const float*)d_in[18];
    const float* fc_w     = (const float*)d_in[19];
    const float* fc_b     = (const float*)d_in[20];
    float* out = (float*)d_out;

    const int M = B_ * SEQ_;                    // 6304
    const size_t SLOT = (size_t)M * DIM_;       // floats
    float* ws  = (float*)d_ws;
    float* x   = ws;
    float* h   = ws + SLOT;
    float* qb  = ws + 2 * SLOT;
    float* kb  = ws + 3 * SLOT;
    float* vb  = ws + 4 * SLOT;
    float* ob  = ws + 5 * SLOT;
    float* mid = qb;                            // MLP hidden aliases q/k/v/o (4 slots = 6304*3072)
    float* hcls = ws + 6 * SLOT;                // 32*768

    dim3 blk(256);
    patch_embed<<<dim3(12, 49), blk, 0, stream>>>(img, conv_w, conv_b, pos_emb, x);
    cls_init<<<(B_ * DIM_ + 255) / 256, blk, 0, stream>>>(cls_tok, pos_emb, x);

    const int MT = (M + BM - 1) / BM;           // 50
    for (int L = 0; L < DEPTH_; L++) {
        layernorm<<<M, blk, 0, stream>>>(x, ln1_g + L * DIM_, ln1_b + L * DIM_, h, 1);
        gemm_nt<EPI_QKV><<<dim3(3 * DIM_ / BN, MT), blk, 0, stream>>>(
            h, qkv_w + (size_t)L * 3 * DIM_ * DIM_, qkv_b + (size_t)L * 3 * DIM_,
            nullptr, M, 3 * DIM_, DIM_, qb, kb, vb);
        attention<<<B_ * HEADS_, blk, 0, stream>>>(qb, kb, vb, ob);
        gemm_nt<EPI_BIAS_RES><<<dim3(DIM_ / BN, MT), blk, 0, stream>>>(
            ob, out_w + (size_t)L * DIM_ * DIM_, out_b + (size_t)L * DIM_,
            x, M, DIM_, DIM_, nullptr, nullptr, nullptr);
        layernorm<<<M, blk, 0, stream>>>(x, ln2_g + L * DIM_, ln2_b + L * DIM_, h, 1);
        gemm_nt<EPI_GELU><<<dim3(MLP_ / BN, MT), blk, 0, stream>>>(
            h, mlp_w1 + (size_t)L * MLP_ * DIM_, mlp_b1 + (size_t)L * MLP_,
            mid, M, MLP_, DIM_, nullptr, nullptr, nullptr);
        gemm_nt<EPI_BIAS_RES><<<dim3(DIM_ / BN, MT), blk, 0, stream>>>(
            mid, mlp_w2 + (size_t)L * DIM_ * MLP_, mlp_b2 + (size_t)L * DIM_,
            x, M, DIM_, MLP_, nullptr, nullptr, nullptr);
    }
    layernorm<<<B_, blk, 0, stream>>>(x, lnf_g, lnf_b, hcls, SEQ_);
    gemm_nt<EPI_BIAS><<<dim3((NCLS_ + BN - 1) / BN, 1), blk, 0, stream>>>(
        hcls, fc_w, fc_b, out, B_, NCLS_, DIM_, nullptr, nullptr, nullptr);
}

// Round 2
// 6232.817 us; speedup vs baseline: 4.3802x; 4.3802x over previous
//
#include <hip/hip_runtime.h>
#include <math.h>

#define B_     32
#define SEQ_   197
#define DIM_   768
#define HEADS_ 12
#define HD_    64
#define MLP_   3072
#define NCLS_  1000
#define DEPTH_ 12
#define MROWS  (B_ * SEQ_)   // 6304
#define MPAD   6400          // padded rows so MFMA A-tile reads never leave our buffers

typedef short s8v __attribute__((ext_vector_type(8)));
typedef float f4v __attribute__((ext_vector_type(4)));

__device__ __forceinline__ unsigned short f2bf(float f) {
    union { float f; unsigned u; } v; v.f = f;
    unsigned r = v.u + 0x7FFFu + ((v.u >> 16) & 1u);   // RNE; inputs are finite
    return (unsigned short)(r >> 16);
}
__device__ __forceinline__ float bf2f(unsigned short h) {
    union { unsigned u; float f; } v; v.u = ((unsigned)h) << 16; return v.f;
}
__device__ __forceinline__ float bflo(unsigned u) {
    union { unsigned x; float f; } v; v.x = u << 16; return v.f;
}
__device__ __forceinline__ float bfhi(unsigned u) {
    union { unsigned x; float f; } v; v.x = u & 0xFFFF0000u; return v.f;
}
__device__ __forceinline__ void async16(const void* g, void* l) {
    __builtin_amdgcn_global_load_lds(
        (const __attribute__((address_space(1))) void*)g,
        (__attribute__((address_space(3))) void*)l, 16, 0, 0);
}

enum { EPI_QKV = 0, EPI_RES = 1, EPI_GELU = 2 };

// C = A(bf16)[M][K] · W(fp32->bf16)[N][K]^T + bias, with fused epilogue.
// A rows MPAD-padded (garbage rows masked at write). N % 128 == 0, K % 64 == 0.
// LDS layout: row m = 128 B (64 bf16) as 8 chunks of 16 B; chunk j stored at slot j^(m&7).
template <int EPI>
__global__ __launch_bounds__(256)
void gemm_bf16(const unsigned short* __restrict__ A, const float* __restrict__ W,
               const float* __restrict__ bias, float* __restrict__ X,
               unsigned short* __restrict__ O, int M, int N, int K,
               unsigned short* __restrict__ qo, unsigned short* __restrict__ ko,
               unsigned short* __restrict__ vo) {
    __shared__ __align__(16) unsigned short As[128 * 64];
    __shared__ __align__(16) unsigned short Bs[128 * 64];
    const int tid = threadIdx.x;
    const int m0 = blockIdx.y * 128, n0 = blockIdx.x * 128;
    const int w = tid >> 6, lane = tid & 63;
    const int wm = w & 1, wn = w >> 1;
    const int qd = lane >> 4, mr = lane & 15;

    f4v acc[4][4] = {};

    for (int k0 = 0; k0 < K; k0 += 64) {
        // A: 16 KB via global_load_lds width-16. chunk c -> LDS offset c*16;
        // content = global chunk (c&7)^(m&7) of row m=c>>3 (swizzle at the source).
#pragma unroll
        for (int r = 0; r < 4; r++) {
            int c = r * 256 + tid;
            int m = c >> 3, slot = c & 7;
            int j = slot ^ (m & 7);
            async16(A + (size_t)(m0 + m) * K + k0 + j * 8, (char*)As + c * 16);
        }
        // W: fp32 load + cvt + swizzled bf16 ds_write (8 B per round).
#pragma unroll
        for (int r = 0; r < 8; r++) {
            int u = r * 256 + tid;
            int n = u >> 4, kq = (u & 15) * 4;
            const float4 wv = *(const float4*)&W[(size_t)(n0 + n) * K + k0 + kq];
            int off = n * 128 + (((kq >> 3) ^ (n & 7)) << 4) + (kq & 7) * 2;
            unsigned p0 = (unsigned)f2bf(wv.x) | ((unsigned)f2bf(wv.y) << 16);
            unsigned p1 = (unsigned)f2bf(wv.z) | ((unsigned)f2bf(wv.w) << 16);
            *(uint2*)((char*)Bs + off) = make_uint2(p0, p1);
        }
        __syncthreads();
#pragma unroll
        for (int s = 0; s < 2; s++) {
            s8v a[4], b[4];
            const int j = s * 4 + qd;
#pragma unroll
            for (int i = 0; i < 4; i++) {
                int ml = wm * 64 + i * 16 + mr;
                a[i] = *(const s8v*)((const char*)As + ml * 128 + ((j ^ (ml & 7)) << 4));
                int nl = wn * 64 + i * 16 + mr;
                b[i] = *(const s8v*)((const char*)Bs + nl * 128 + ((j ^ (nl & 7)) << 4));
            }
#pragma unroll
            for (int i = 0; i < 4; i++)
#pragma unroll
                for (int jj = 0; jj < 4; jj++)
                    acc[i][jj] = __builtin_amdgcn_mfma_f32_16x16x32_bf16(
                        a[i], b[jj], acc[i][jj], 0, 0, 0);
        }
        __syncthreads();
    }

    // C/D layout: col = lane&15, row = (lane>>4)*4 + reg.
#pragma unroll
    for (int i = 0; i < 4; i++) {
#pragma unroll
        for (int jj = 0; jj < 4; jj++) {
            const int n = n0 + wn * 64 + jj * 16 + mr;
            const float bn = bias[n];
#pragma unroll
            for (int r = 0; r < 4; r++) {
                const int m = m0 + wm * 64 + i * 16 + qd * 4 + r;
                if (m >= M) continue;
                float val = acc[i][jj][r] + bn;
                if constexpr (EPI == EPI_RES) {
                    X[(size_t)m * N + n] += val;   // fp32 residual accumulate
                } else if constexpr (EPI == EPI_GELU) {
                    O[(size_t)m * N + n] =
                        f2bf(0.5f * val * (1.f + erff(val * 0.70710678118654752f)));
                } else {  // EPI_QKV: scatter to [B][HEADS][SEQ][HD] bf16
                    int b = m / SEQ_, s = m - b * SEQ_;
                    int i3 = n / DIM_, nr = n - i3 * DIM_;
                    int hh = nr >> 6, d = nr & 63;
                    unsigned short* dst = (i3 == 0) ? qo : (i3 == 1) ? ko : vo;
                    dst[(((size_t)(b * HEADS_ + hh)) * SEQ_ + s) * HD_ + d] = f2bf(val);
                }
            }
        }
    }
}

// Patch embedding, fp32 (7.4 GF, run once): gathered GEMM M=6272 N=768 K=768.
#define BM 128
#define BN 64
#define BK 16
__launch_bounds__(256)
__global__ void patch_embed(const float* __restrict__ img, const float* __restrict__ cw,
                            const float* __restrict__ cb, const float* __restrict__ pos,
                            float* __restrict__ x) {
    __shared__ __align__(16) float As[BK][BM + 4];
    __shared__ __align__(16) float Ws[BK][BN + 4];
    const int tid = threadIdx.x;
    const int tx = tid & 15, ty = tid >> 4;
    const int m0 = blockIdx.y * BM;
    const int n0 = blockIdx.x * BN;
    float acc[8][4];
#pragma unroll
    for (int i = 0; i < 8; i++)
#pragma unroll
        for (int j = 0; j < 4; j++) acc[i][j] = 0.f;

    for (int k0 = 0; k0 < 768; k0 += BK) {
#pragma unroll
        for (int it = 0; it < 2; it++) {
            int e4 = tid + it * 256;
            int ml = e4 >> 2;
            int kl = (e4 & 3) * 4;
            int m = m0 + ml;
            int b = m / 196, pp = m - b * 196;
            int gh = pp / 14, gw = pp - gh * 14;
            int k = k0 + kl;
            int c = k >> 8, r = (k >> 4) & 15, qq = k & 15;
            const float4 val = *(const float4*)
                &img[(((size_t)(b * 3 + c) * 224) + gh * 16 + r) * 224 + gw * 16 + qq];
            As[kl + 0][ml] = val.x; As[kl + 1][ml] = val.y;
            As[kl + 2][ml] = val.z; As[kl + 3][ml] = val.w;
        }
        {
            int nl = tid >> 2;
            int kl = (tid & 3) * 4;
            const float4 val = *(const float4*)&cw[(size_t)(n0 + nl) * 768 + k0 + kl];
            Ws[kl + 0][nl] = val.x; Ws[kl + 1][nl] = val.y;
            Ws[kl + 2][nl] = val.z; Ws[kl + 3][nl] = val.w;
        }
        __syncthreads();
#pragma unroll
        for (int kk = 0; kk < BK; kk++) {
            float4 a0 = *(const float4*)&As[kk][ty * 8];
            float4 a1 = *(const float4*)&As[kk][ty * 8 + 4];
            float4 w0 = *(const float4*)&Ws[kk][tx * 4];
            float av[8] = {a0.x, a0.y, a0.z, a0.w, a1.x, a1.y, a1.z, a1.w};
            float wv[4] = {w0.x, w0.y, w0.z, w0.w};
#pragma unroll
            for (int i = 0; i < 8; i++)
#pragma unroll
                for (int j = 0; j < 4; j++) acc[i][j] += av[i] * wv[j];
        }
        __syncthreads();
    }
#pragma unroll
    for (int i = 0; i < 8; i++) {
        int m = m0 + ty * 8 + i;
        int b = m / 196, pp = m - b * 196;
        size_t row = (size_t)b * SEQ_ + 1 + pp;
#pragma unroll
        for (int j = 0; j < 4; j++) {
            int n = n0 + tx * 4 + j;
            x[row * DIM_ + n] = acc[i][j] + cb[n] + pos[(size_t)(1 + pp) * DIM_ + n];
        }
    }
}

// fp32 head GEMM (M=32, N=1000, K=768) — tiny, keep simple.
__launch_bounds__(256)
__global__ void gemm_f32_bias(const float* __restrict__ A, const float* __restrict__ W,
                              const float* __restrict__ bias, float* __restrict__ C,
                              int M, int N, int K) {
    __shared__ __align__(16) float As[BK][BM + 4];
    __shared__ __align__(16) float Ws[BK][BN + 4];
    const int tid = threadIdx.x;
    const int tx = tid & 15, ty = tid >> 4;
    const int m0 = blockIdx.y * BM;
    const int n0 = blockIdx.x * BN;
    float acc[8][4];
#pragma unroll
    for (int i = 0; i < 8; i++)
#pragma unroll
        for (int j = 0; j < 4; j++) acc[i][j] = 0.f;

    for (int k0 = 0; k0 < K; k0 += BK) {
#pragma unroll
        for (int it = 0; it < 2; it++) {
            int e4 = tid + it * 256;
            int ml = e4 >> 2;
            int kl = (e4 & 3) * 4;
            int m = m0 + ml;
            float4 val = make_float4(0.f, 0.f, 0.f, 0.f);
            if (m < M) val = *(const float4*)&A[(size_t)m * K + k0 + kl];
            As[kl + 0][ml] = val.x; As[kl + 1][ml] = val.y;
            As[kl + 2][ml] = val.z; As[kl + 3][ml] = val.w;
        }
        {
            int nl = tid >> 2;
            int kl = (tid & 3) * 4;
            int n = n0 + nl;
            float4 val = make_float4(0.f, 0.f, 0.f, 0.f);
            if (n < N) val = *(const float4*)&W[(size_t)n * K + k0 + kl];
            Ws[kl + 0][nl] = val.x; Ws[kl + 1][nl] = val.y;
            Ws[kl + 2][nl] = val.z; Ws[kl + 3][nl] = val.w;
        }
        __syncthreads();
#pragma unroll
        for (int kk = 0; kk < BK; kk++) {
            float4 a0 = *(const float4*)&As[kk][ty * 8];
            float4 a1 = *(const float4*)&As[kk][ty * 8 + 4];
            float4 w0 = *(const float4*)&Ws[kk][tx * 4];
            float av[8] = {a0.x, a0.y, a0.z, a0.w, a1.x, a1.y, a1.z, a1.w};
            float wv[4] = {w0.x, w0.y, w0.z, w0.w};
#pragma unroll
            for (int i = 0; i < 8; i++)
#pragma unroll
                for (int j = 0; j < 4; j++) acc[i][j] += av[i] * wv[j];
        }
        __syncthreads();
    }
#pragma unroll
    for (int i = 0; i < 8; i++) {
        int m = m0 + ty * 8 + i;
        if (m >= M) continue;
#pragma unroll
        for (int j = 0; j < 4; j++) {
            int n = n0 + tx * 4 + j;
            if (n >= N) continue;
            C[(size_t)m * N + n] = acc[i][j] + bias[n];
        }
    }
}

__global__ void cls_init(const float* __restrict__ cls, const float* __restrict__ pos,
                         float* __restrict__ x) {
    int idx = blockIdx.x * 256 + threadIdx.x;
    if (idx >= B_ * DIM_) return;
    int b = idx / DIM_, d = idx - b * DIM_;
    x[(size_t)b * SEQ_ * DIM_ + d] = cls[d] + pos[d];
}

// LayerNorm, fp32 in -> OT out (bf16 bits for trunk, float for final CLS rows).
template <typename OT>
__global__ __launch_bounds__(256)
void layernorm(const float* __restrict__ in, const float* __restrict__ g,
               const float* __restrict__ bta, OT* __restrict__ out, int row_mul) {
    const float* xr = in + (size_t)blockIdx.x * row_mul * DIM_;
    OT* orow = out + (size_t)blockIdx.x * DIM_;
    int tid = threadIdx.x;
    float v0 = xr[tid], v1 = xr[tid + 256], v2 = xr[tid + 512];
    __shared__ float s1[256], s2[256];
    s1[tid] = v0 + v1 + v2;
    s2[tid] = v0 * v0 + v1 * v1 + v2 * v2;
    __syncthreads();
    for (int off = 128; off > 0; off >>= 1) {
        if (tid < off) { s1[tid] += s1[tid + off]; s2[tid] += s2[tid + off]; }
        __syncthreads();
    }
    float mean = s1[0] * (1.f / 768.f);
    float var = s2[0] * (1.f / 768.f) - mean * mean;
    float rstd = rsqrtf(var + 1e-6f);
#pragma unroll
    for (int c = 0; c < 3; c++) {
        int idx = tid + c * 256;
        float vv = (c == 0) ? v0 : (c == 1) ? v1 : v2;
        float val = (vv - mean) * rstd * g[idx] + bta[idx];
        if constexpr (sizeof(OT) == 2) orow[idx] = f2bf(val);
        else                           orow[idx] = val;
    }
}

// Attention v3: grid (B*H, 2). K/V staged bf16+swizzled in LDS; 4 q-rows per wave
// per pass; P in LDS bf16; softmax via 64-lane shuffles; tpar splits t over half-waves.
__global__ __launch_bounds__(256)
void attention(const unsigned short* __restrict__ q, const unsigned short* __restrict__ k,
               const unsigned short* __restrict__ v, unsigned short* __restrict__ ob) {
    __shared__ __align__(16) unsigned short kf[SEQ_ * 64];   // swizzled [t][d]
    __shared__ __align__(16) unsigned short vf[SEQ_ * 64];
    __shared__ unsigned short pbuf[4][4][256];
    __shared__ __align__(16) float qbuf[4][4][64];
    const int bh = blockIdx.x, half = blockIdx.y;
    const int bi = bh / HEADS_, hh = bh - bi * HEADS_;
    const unsigned short* qp = q + (size_t)bh * SEQ_ * HD_;
    const unsigned short* kp = k + (size_t)bh * SEQ_ * HD_;
    const unsigned short* vp = v + (size_t)bh * SEQ_ * HD_;
    unsigned short* op = ob + (size_t)bi * SEQ_ * DIM_ + hh * HD_;
    const int tid = threadIdx.x;

    for (int c = tid; c < SEQ_ * 8; c += 256) {
        int t = c >> 3, ds = c & 7;
        int dst = t * 128 + ((ds ^ (t & 7)) << 4);
        *(uint4*)((char*)kf + dst) = *(const uint4*)((const char*)kp + c * 16);
        *(uint4*)((char*)vf + dst) = *(const uint4*)((const char*)vp + c * 16);
    }
    __syncthreads();

    const int w = tid >> 6, lane = tid & 63;
    const int rows = half ? (SEQ_ - 100) : 100;
    const int sbase = half * 100;
    const int t3v = (lane + 192 < SEQ_);
    const int tcl[4] = {lane, lane + 64, lane + 128, t3v ? lane + 192 : SEQ_ - 1};
    const int tpar = lane >> 5, d2 = (lane & 31) * 2;

    for (int g = 0; g * 16 + w * 4 < rows; g++) {
        float sc[4][4];
#pragma unroll
        for (int j = 0; j < 4; j++) {
            int sl = g * 16 + w * 4 + j;
            int s = sbase + ((sl < rows) ? sl : 0);
            qbuf[w][j][lane] = bf2f(qp[s * HD_ + lane]);
#pragma unroll
            for (int ti = 0; ti < 4; ti++) sc[j][ti] = 0.f;
        }
        for (int dd = 0; dd < 64; dd += 8) {
            uint4 kw[4];
#pragma unroll
            for (int ti = 0; ti < 4; ti++) {
                int t = tcl[ti];
                kw[ti] = *(const uint4*)((const char*)kf + t * 128 +
                                         (((dd >> 3) ^ (t & 7)) << 4));
            }
#pragma unroll
            for (int j = 0; j < 4; j++) {
                const float4 q0 = *(const float4*)&qbuf[w][j][dd];
                const float4 q1 = *(const float4*)&qbuf[w][j][dd + 4];
#pragma unroll
                for (int ti = 0; ti < 4; ti++) {
                    sc[j][ti] += q0.x * bflo(kw[ti].x) + q0.y * bfhi(kw[ti].x)
                               + q0.z * bflo(kw[ti].y) + q0.w * bfhi(kw[ti].y)
                               + q1.x * bflo(kw[ti].z) + q1.y * bfhi(kw[ti].z)
                               + q1.z * bflo(kw[ti].w) + q1.w * bfhi(kw[ti].w);
                }
            }
        }
        float o0[4], o1[4];
#pragma unroll
        for (int j = 0; j < 4; j++) {
            if (!t3v) sc[j][3] = -INFINITY;
#pragma unroll
            for (int ti = 0; ti < 4; ti++) sc[j][ti] *= 0.125f;
            float mx = fmaxf(fmaxf(sc[j][0], sc[j][1]), fmaxf(sc[j][2], sc[j][3]));
#pragma unroll
            for (int off = 32; off > 0; off >>= 1) mx = fmaxf(mx, __shfl_xor(mx, off));
            float e0 = __expf(sc[j][0] - mx), e1 = __expf(sc[j][1] - mx);
            float e2 = __expf(sc[j][2] - mx), e3 = __expf(sc[j][3] - mx);
            float sum = e0 + e1 + e2 + e3;
#pragma unroll
            for (int off = 32; off > 0; off >>= 1) sum += __shfl_xor(sum, off);
            float inv = 1.f / sum;
            pbuf[w][j][lane]       = f2bf(e0 * inv);
            pbuf[w][j][lane + 64]  = f2bf(e1 * inv);
            pbuf[w][j][lane + 128] = f2bf(e2 * inv);
            pbuf[w][j][lane + 192] = f2bf(t3v ? e3 * inv : 0.f);
            o0[j] = 0.f; o1[j] = 0.f;
        }
        for (int tt = 0; tt < 99; tt++) {
            int t = 2 * tt + tpar;
            if (t < SEQ_) {
                unsigned vv = *(const unsigned*)((const char*)vf + t * 128 +
                                                 (((d2 >> 3) ^ (t & 7)) << 4) + (d2 & 7) * 2);
                float v0 = bflo(vv), v1 = bfhi(vv);
#pragma unroll
                for (int j = 0; j < 4; j++) {
                    float pj = bf2f(pbuf[w][j][t]);
                    o0[j] += pj * v0;
                    o1[j] += pj * v1;
                }
            }
        }
#pragma unroll
        for (int j = 0; j < 4; j++) {
            o0[j] += __shfl_xor(o0[j], 32);
            o1[j] += __shfl_xor(o1[j], 32);
            int sl = g * 16 + w * 4 + j;
            if (tpar == 0 && sl < rows) {
                int s = sbase + sl;
                unsigned pk = (unsigned)f2bf(o0[j]) | ((unsigned)f2bf(o1[j]) << 16);
                *(unsigned*)((char*)op + ((size_t)s * DIM_ + d2) * 2) = pk;
            }
        }
    }
}

extern "C" void kernel_launch(void* const* d_in, const int* in_sizes, int n_in,
                              void* d_out, int out_size, void* d_ws, size_t ws_size,
                              hipStream_t stream) {
    const float* img     = (const float*)d_in[0];
    const float* conv_w  = (const float*)d_in[1];
    const float* conv_b  = (const float*)d_in[2];
    const float* cls_tok = (const float*)d_in[3];
    const float* pos_emb = (const float*)d_in[4];
    const float* ln1_g   = (const float*)d_in[5];
    const float* ln1_b   = (const float*)d_in[6];
    const float* qkv_w   = (const float*)d_in[7];
    const float* qkv_b   = (const float*)d_in[8];
    const float* out_w   = (const float*)d_in[9];
    const float* out_b   = (const float*)d_in[10];
    const float* ln2_g   = (const float*)d_in[11];
    const float* ln2_b   = (const float*)d_in[12];
    const float* mlp_w1  = (const float*)d_in[13];
    const float* mlp_b1  = (const float*)d_in[14];
    const float* mlp_w2  = (const float*)d_in[15];
    const float* mlp_b2  = (const float*)d_in[16];
    const float* lnf_g   = (const float*)d_in[17];
    const float* lnf_b   = (const float*)d_in[18];
    const float* fc_w    = (const float*)d_in[19];
    const float* fc_b    = (const float*)d_in[20];
    float* out = (float*)d_out;

    char* p = (char*)d_ws;
    float* x = (float*)p;                 p += (size_t)MROWS * DIM_ * 4;   // fp32 residual
    unsigned short* h   = (unsigned short*)p; p += (size_t)MPAD * DIM_ * 2; // bf16 LN out
    unsigned short* qb  = (unsigned short*)p; p += (size_t)MROWS * DIM_ * 2;
    unsigned short* kb  = (unsigned short*)p; p += (size_t)MROWS * DIM_ * 2;
    unsigned short* vb  = (unsigned short*)p; p += (size_t)MROWS * DIM_ * 2;
    unsigned short* obuf= (unsigned short*)p; p += (size_t)MPAD * DIM_ * 2;
    unsigned short* mid = (unsigned short*)p; p += (size_t)MPAD * MLP_ * 2;
    float* hcls = (float*)p;              p += (size_t)B_ * DIM_ * 4;
    // total ~102.5 MB

    dim3 blk(256);
    patch_embed<<<dim3(12, 49), blk, 0, stream>>>(img, conv_w, conv_b, pos_emb, x);
    cls_init<<<(B_ * DIM_ + 255) / 256, blk, 0, stream>>>(cls_tok, pos_emb, x);

    const int MT = (MROWS + 127) / 128;   // 50
    for (int L = 0; L < DEPTH_; L++) {
        layernorm<unsigned short><<<MROWS, blk, 0, stream>>>(
            x, ln1_g + L * DIM_, ln1_b + L * DIM_, h, 1);
        gemm_bf16<EPI_QKV><<<dim3(3 * DIM_ / 128, MT), blk, 0, stream>>>(
            h, qkv_w + (size_t)L * 3 * DIM_ * DIM_, qkv_b + (size_t)L * 3 * DIM_,
            nullptr, nullptr, MROWS, 3 * DIM_, DIM_, qb, kb, vb);
        attention<<<dim3(B_ * HEADS_, 2), blk, 0, stream>>>(qb, kb, vb, obuf);
        gemm_bf16<EPI_RES><<<dim3(DIM_ / 128, MT), blk, 0, stream>>>(
            obuf, out_w + (size_t)L * DIM_ * DIM_, out_b + (size_t)L * DIM_,
            x, nullptr, MROWS, DIM_, DIM_, nullptr, nullptr, nullptr);
        layernorm<unsigned short><<<MROWS, blk, 0, stream>>>(
            x, ln2_g + L * DIM_, ln2_b + L * DIM_, h, 1);
        gemm_bf16<EPI_GELU><<<dim3(MLP_ / 128, MT), blk, 0, stream>>>(
            h, mlp_w1 + (size_t)L * MLP_ * DIM_, mlp_b1 + (size_t)L * MLP_,
            nullptr, mid, MROWS, MLP_, DIM_, nullptr, nullptr, nullptr);
        gemm_bf16<EPI_RES><<<dim3(DIM_ / 128, MT), blk, 0, stream>>>(
            mid, mlp_w2 + (size_t)L * DIM_ * MLP_, mlp_b2 + (size_t)L * DIM_,
            x, nullptr, MROWS, DIM_, MLP_, nullptr, nullptr, nullptr);
    }
    layernorm<float><<<B_, blk, 0, stream>>>(x, lnf_g, lnf_b, hcls, SEQ_);
    gemm_f32_bias<<<dim3((NCLS_ + BN - 1) / BN, 1), blk, 0, stream>>>(
        hcls, fc_w, fc_b, out, B_, NCLS_, DIM_);
}

// Round 3
// 3893.706 us; speedup vs baseline: 7.0116x; 1.6007x over previous
//
#include <hip/hip_runtime.h>
#include <math.h>

#define B_     32
#define SEQ_   197
#define DIM_   768
#define HEADS_ 12
#define HD_    64
#define MLP_   3072
#define NCLS_  1000
#define DEPTH_ 12
#define MROWS  (B_ * SEQ_)   // 6304
#define MPAD   6400          // padded rows so MFMA A-tile reads never leave our buffers

// per-layer bf16 weight pack: [qkv 2304x768][out 768x768][mlp1 3072x768][mlp2 768x3072]
#define WOFF_QKV 0
#define WOFF_OUT 1769472
#define WOFF_M1  2359296
#define WOFF_M2  4718592
#define LW_      7077888

typedef short s8v __attribute__((ext_vector_type(8)));
typedef float f4v __attribute__((ext_vector_type(4)));

__device__ __forceinline__ unsigned short f2bf(float f) {
    union { float f; unsigned u; } v; v.f = f;
    unsigned r = v.u + 0x7FFFu + ((v.u >> 16) & 1u);   // RNE; inputs finite
    return (unsigned short)(r >> 16);
}
__device__ __forceinline__ float bf2f(unsigned short h) {
    union { unsigned u; float f; } v; v.u = ((unsigned)h) << 16; return v.f;
}
__device__ __forceinline__ void async16(const void* g, void* l) {
    __builtin_amdgcn_global_load_lds(
        (const __attribute__((address_space(1))) void*)g,
        (__attribute__((address_space(3))) void*)l, 16, 0, 0);
}

enum { EPI_QKV = 0, EPI_RES = 1, EPI_GELU = 2 };

// C = A(bf16)[M][K] . W[N][K]^T + bias, fused epilogue. WB: W already bf16 (async16
// staging); else fp32 W converted during staging (fallback). A rows MPAD-padded.
// LDS: row m = 8 chunks of 16B; chunk j stored at slot j^(m&7) (XOR swizzle).
template <int EPI, bool WB>
__global__ __launch_bounds__(256)
void gemm_bf16(const unsigned short* __restrict__ A, const void* __restrict__ Wv,
               const float* __restrict__ bias, float* __restrict__ X,
               unsigned short* __restrict__ O, int M, int N, int K,
               unsigned short* __restrict__ qo, unsigned short* __restrict__ ko,
               unsigned short* __restrict__ vo) {
    __shared__ __align__(16) unsigned short As[128 * 64];
    __shared__ __align__(16) unsigned short Bs[128 * 64];
    const int tid = threadIdx.x;
    const int m0 = blockIdx.y * 128, n0 = blockIdx.x * 128;
    const int w = tid >> 6, lane = tid & 63;
    const int wm = w & 1, wn = w >> 1;
    const int qd = lane >> 4, mr = lane & 15;

    f4v acc[4][4] = {};

    for (int k0 = 0; k0 < K; k0 += 64) {
#pragma unroll
        for (int r = 0; r < 4; r++) {
            int c = r * 256 + tid;
            int m = c >> 3, slot = c & 7;
            int j = slot ^ (m & 7);
            async16(A + (size_t)(m0 + m) * K + k0 + j * 8, (char*)As + c * 16);
        }
        if constexpr (WB) {
            const unsigned short* Wb = (const unsigned short*)Wv;
#pragma unroll
            for (int r = 0; r < 4; r++) {
                int c = r * 256 + tid;
                int n = c >> 3, slot = c & 7;
                int j = slot ^ (n & 7);
                async16(Wb + (size_t)(n0 + n) * K + k0 + j * 8, (char*)Bs + c * 16);
            }
        } else {
            const float* Wf = (const float*)Wv;
#pragma unroll
            for (int r = 0; r < 8; r++) {
                int u = r * 256 + tid;
                int n = u >> 4, kq = (u & 15) * 4;
                const float4 wv = *(const float4*)&Wf[(size_t)(n0 + n) * K + k0 + kq];
                int off = n * 128 + (((kq >> 3) ^ (n & 7)) << 4) + (kq & 7) * 2;
                unsigned p0 = (unsigned)f2bf(wv.x) | ((unsigned)f2bf(wv.y) << 16);
                unsigned p1 = (unsigned)f2bf(wv.z) | ((unsigned)f2bf(wv.w) << 16);
                *(uint2*)((char*)Bs + off) = make_uint2(p0, p1);
            }
        }
        __syncthreads();
#pragma unroll
        for (int s = 0; s < 2; s++) {
            s8v a[4], b[4];
            const int j = s * 4 + qd;
#pragma unroll
            for (int i = 0; i < 4; i++) {
                int ml = wm * 64 + i * 16 + mr;
                a[i] = *(const s8v*)((const char*)As + ml * 128 + ((j ^ (ml & 7)) << 4));
                int nl = wn * 64 + i * 16 + mr;
                b[i] = *(const s8v*)((const char*)Bs + nl * 128 + ((j ^ (nl & 7)) << 4));
            }
#pragma unroll
            for (int i = 0; i < 4; i++)
#pragma unroll
                for (int jj = 0; jj < 4; jj++)
                    acc[i][jj] = __builtin_amdgcn_mfma_f32_16x16x32_bf16(
                        a[i], b[jj], acc[i][jj], 0, 0, 0);
        }
        __syncthreads();
    }

    // C/D layout: col = lane&15, row = (lane>>4)*4 + reg.
#pragma unroll
    for (int i = 0; i < 4; i++) {
#pragma unroll
        for (int jj = 0; jj < 4; jj++) {
            const int n = n0 + wn * 64 + jj * 16 + mr;
            const float bn = bias[n];
#pragma unroll
            for (int r = 0; r < 4; r++) {
                const int m = m0 + wm * 64 + i * 16 + qd * 4 + r;
                if (m >= M) continue;
                float val = acc[i][jj][r] + bn;
                if constexpr (EPI == EPI_RES) {
                    X[(size_t)m * N + n] += val;   // fp32 residual accumulate
                } else if constexpr (EPI == EPI_GELU) {
                    O[(size_t)m * N + n] =
                        f2bf(0.5f * val * (1.f + erff(val * 0.70710678118654752f)));
                } else {  // EPI_QKV: scatter to [B][HEADS][SEQ][HD] bf16
                    int b = m / SEQ_, s = m - b * SEQ_;
                    int i3 = n / DIM_, nr = n - i3 * DIM_;
                    int hh = nr >> 6, d = nr & 63;
                    unsigned short* dst = (i3 == 0) ? qo : (i3 == 1) ? ko : vo;
                    dst[(((size_t)(b * HEADS_ + hh)) * SEQ_ + s) * HD_ + d] = f2bf(val);
                }
            }
        }
    }
}

// MFMA attention. grid(B*H, 4): 64 query rows per block, 16 per wave.
// LDS reuse: KV region holds K[208][72] for QK^T, then V^T[64][232] for PV.
__global__ __launch_bounds__(256)
void attention_mfma(const unsigned short* __restrict__ q, const unsigned short* __restrict__ k,
                    const unsigned short* __restrict__ v, unsigned short* __restrict__ ob) {
    __shared__ __align__(16) char smem[59648];
    unsigned short* KV = (unsigned short*)smem;            // 29952 B
    unsigned short* P  = (unsigned short*)(smem + 29952);  // 4 waves x [16][232] bf16
    const int bh = blockIdx.x, sblk = blockIdx.y;
    const int bi = bh / HEADS_, hh = bh - bi * HEADS_;
    const unsigned short* qp = q + (size_t)bh * SEQ_ * HD_;
    const unsigned short* kp = k + (size_t)bh * SEQ_ * HD_;
    const unsigned short* vp = v + (size_t)bh * SEQ_ * HD_;
    unsigned short* op = ob + (size_t)bi * SEQ_ * DIM_ + hh * HD_;
    const int tid = threadIdx.x;
    const int w = tid >> 6, lane = tid & 63;
    const int mq = lane & 15, quad = lane >> 4;

    // stage K[197][64] -> rows stride 72 (2-way-free banks); zero rows 197..207
    for (int c = tid; c < 197 * 8; c += 256) {
        int t = c >> 3, ch = c & 7;
        *(uint4*)(KV + t * 72 + ch * 8) = *(const uint4*)(kp + c * 8);
    }
    if (tid < 88) {
        int t = 197 + (tid >> 3), ch = tid & 7;
        *(uint4*)(KV + t * 72 + ch * 8) = make_uint4(0, 0, 0, 0);
    }
    // Q A-frags straight from global: A[m=lane&15][k=quad*8+j]
    const int sA = sblk * 64 + w * 16 + mq;   // may exceed 196: reads stay inside ws
    s8v a0 = *(const s8v*)(qp + sA * 64 + quad * 8);
    s8v a1 = *(const s8v*)(qp + sA * 64 + 32 + quad * 8);
    __syncthreads();

    f4v acc[13] = {};
#pragma unroll
    for (int ti = 0; ti < 13; ti++) {
        const unsigned short* kr = KV + (ti * 16 + mq) * 72 + quad * 8;
        s8v b0 = *(const s8v*)kr;
        s8v b1 = *(const s8v*)(kr + 32);
        acc[ti] = __builtin_amdgcn_mfma_f32_16x16x32_bf16(a0, b0, acc[ti], 0, 0, 0);
        acc[ti] = __builtin_amdgcn_mfma_f32_16x16x32_bf16(a1, b1, acc[ti], 0, 0, 0);
    }
    // row softmax in-register; rows = quad*4+r, cols = ti*16+mq
    float mxr[4] = {-3e38f, -3e38f, -3e38f, -3e38f};
#pragma unroll
    for (int ti = 0; ti < 13; ti++) {
        const bool msk = (ti == 12) && (mq >= 5);   // t >= 197
#pragma unroll
        for (int r = 0; r < 4; r++) {
            float vs = msk ? -3e38f : acc[ti][r] * 0.125f;
            acc[ti][r] = vs;
            mxr[r] = fmaxf(mxr[r], vs);
        }
    }
#pragma unroll
    for (int r = 0; r < 4; r++)
#pragma unroll
        for (int off = 1; off < 16; off <<= 1)
            mxr[r] = fmaxf(mxr[r], __shfl_xor(mxr[r], off));
    float sum[4] = {0.f, 0.f, 0.f, 0.f};
#pragma unroll
    for (int ti = 0; ti < 13; ti++)
#pragma unroll
        for (int r = 0; r < 4; r++) {
            float e = __expf(acc[ti][r] - mxr[r]);
            acc[ti][r] = e;
            sum[r] += e;
        }
#pragma unroll
    for (int r = 0; r < 4; r++) {
#pragma unroll
        for (int off = 1; off < 16; off <<= 1) sum[r] += __shfl_xor(sum[r], off);
        sum[r] = 1.f / sum[r];
    }
    unsigned short* Pw = P + w * 16 * 232;   // wave-private: no barrier needed
#pragma unroll
    for (int ti = 0; ti < 13; ti++)
#pragma unroll
        for (int r = 0; r < 4; r++)
            Pw[(quad * 4 + r) * 232 + ti * 16 + mq] = f2bf(acc[ti][r] * sum[r]);
    {   // zero P cols 208..223 (PV K-pad)
        int r2 = lane >> 2, c2 = 208 + (lane & 3) * 4;
        *(uint2*)(Pw + r2 * 232 + c2) = make_uint2(0, 0);
    }
    __syncthreads();   // all waves done reading K
    // stage V^T[64][232]; zero cols 197..223
    for (int c = tid; c < 197 * 64; c += 256) {
        int t = c >> 6, d = c & 63;
        KV[d * 232 + t] = vp[c];
    }
    for (int c = tid; c < 27 * 64; c += 256) {
        int t = 197 + (c >> 6), d = c & 63;
        KV[d * 232 + t] = 0;
    }
    __syncthreads();
    f4v po[4] = {};
#pragma unroll
    for (int kt = 0; kt < 7; kt++) {
        s8v pa = *(const s8v*)(Pw + mq * 232 + kt * 32 + quad * 8);
#pragma unroll
        for (int nt = 0; nt < 4; nt++) {
            s8v vb2 = *(const s8v*)(KV + (nt * 16 + mq) * 232 + kt * 32 + quad * 8);
            po[nt] = __builtin_amdgcn_mfma_f32_16x16x32_bf16(pa, vb2, po[nt], 0, 0, 0);
        }
    }
#pragma unroll
    for (int nt = 0; nt < 4; nt++)
#pragma unroll
        for (int r = 0; r < 4; r++) {
            int s = sblk * 64 + w * 16 + quad * 4 + r;
            if (s < SEQ_) op[(size_t)s * DIM_ + nt * 16 + mq] = f2bf(po[nt][r]);
        }
}

// Patch embedding as bf16 MFMA GEMM: M=6272 (b,gh,gw), N=768, K=768 (c,r,q).
__global__ __launch_bounds__(256)
void patch_embed_mfma(const unsigned short* __restrict__ imgb,
                      const unsigned short* __restrict__ cwb,
                      const float* __restrict__ cb, const float* __restrict__ pos,
                      float* __restrict__ x) {
    __shared__ __align__(16) unsigned short As[128 * 64];
    __shared__ __align__(16) unsigned short Bs[128 * 64];
    const int tid = threadIdx.x;
    const int m0 = blockIdx.y * 128, n0 = blockIdx.x * 128;
    const int w = tid >> 6, lane = tid & 63;
    const int wm = w & 1, wn = w >> 1;
    const int qd = lane >> 4, mr = lane & 15;

    int rowoff[4], jj4[4];
#pragma unroll
    for (int r = 0; r < 4; r++) {
        int c = r * 256 + tid;
        int m = c >> 3, slot = c & 7;
        jj4[r] = slot ^ (m & 7);
        int mg = m0 + m;
        int b = mg / 196, pp = mg - b * 196;
        int gh = pp / 14, gw = pp - gh * 14;
        rowoff[r] = ((b * 3) * 224 + gh * 16) * 224 + gw * 16;
    }
    f4v acc[4][4] = {};
    for (int k0 = 0; k0 < 768; k0 += 64) {
#pragma unroll
        for (int r = 0; r < 4; r++) {
            int c = r * 256 + tid;
            int kb = k0 + jj4[r] * 8;
            int cc = kb >> 8, rr = (kb >> 4) & 15, qh = kb & 15;
            async16(imgb + rowoff[r] + (cc * 224 + rr) * 224 + qh, (char*)As + c * 16);
        }
#pragma unroll
        for (int r = 0; r < 4; r++) {
            int c = r * 256 + tid;
            int n = c >> 3, slot = c & 7;
            int j = slot ^ (n & 7);
            async16(cwb + (size_t)(n0 + n) * 768 + k0 + j * 8, (char*)Bs + c * 16);
        }
        __syncthreads();
#pragma unroll
        for (int s = 0; s < 2; s++) {
            s8v a[4], b[4];
            const int j = s * 4 + qd;
#pragma unroll
            for (int i = 0; i < 4; i++) {
                int ml = wm * 64 + i * 16 + mr;
                a[i] = *(const s8v*)((const char*)As + ml * 128 + ((j ^ (ml & 7)) << 4));
                int nl = wn * 64 + i * 16 + mr;
                b[i] = *(const s8v*)((const char*)Bs + nl * 128 + ((j ^ (nl & 7)) << 4));
            }
#pragma unroll
            for (int i = 0; i < 4; i++)
#pragma unroll
                for (int jj = 0; jj < 4; jj++)
                    acc[i][jj] = __builtin_amdgcn_mfma_f32_16x16x32_bf16(
                        a[i], b[jj], acc[i][jj], 0, 0, 0);
        }
        __syncthreads();
    }
#pragma unroll
    for (int i = 0; i < 4; i++)
#pragma unroll
        for (int jj = 0; jj < 4; jj++) {
            const int n = n0 + wn * 64 + jj * 16 + mr;
            const float bn = cb[n];
#pragma unroll
            for (int r = 0; r < 4; r++) {
                const int m = m0 + wm * 64 + i * 16 + qd * 4 + r;
                int b = m / 196, pp = m - b * 196;
                x[((size_t)(b * 197 + 1 + pp)) * 768 + n] =
                    acc[i][jj][r] + bn + pos[(size_t)(1 + pp) * 768 + n];
            }
        }
}

// fp32 patch embed fallback (tier C) — round-1 kernel.
#define BM 128
#define BN 64
#define BK 16
__launch_bounds__(256)
__global__ void patch_embed(const float* __restrict__ img, const float* __restrict__ cw,
                            const float* __restrict__ cb, const float* __restrict__ pos,
                            float* __restrict__ x) {
    __shared__ __align__(16) float As[BK][BM + 4];
    __shared__ __align__(16) float Ws[BK][BN + 4];
    const int tid = threadIdx.x;
    const int tx = tid & 15, ty = tid >> 4;
    const int m0 = blockIdx.y * BM;
    const int n0 = blockIdx.x * BN;
    float acc[8][4];
#pragma unroll
    for (int i = 0; i < 8; i++)
#pragma unroll
        for (int j = 0; j < 4; j++) acc[i][j] = 0.f;

    for (int k0 = 0; k0 < 768; k0 += BK) {
#pragma unroll
        for (int it = 0; it < 2; it++) {
            int e4 = tid + it * 256;
            int ml = e4 >> 2;
            int kl = (e4 & 3) * 4;
            int m = m0 + ml;
            int b = m / 196, pp = m - b * 196;
            int gh = pp / 14, gw = pp - gh * 14;
            int k = k0 + kl;
            int c = k >> 8, r = (k >> 4) & 15, qq = k & 15;
            const float4 val = *(const float4*)
                &img[(((size_t)(b * 3 + c) * 224) + gh * 16 + r) * 224 + gw * 16 + qq];
            As[kl + 0][ml] = val.x; As[kl + 1][ml] = val.y;
            As[kl + 2][ml] = val.z; As[kl + 3][ml] = val.w;
        }
        {
            int nl = tid >> 2;
            int kl = (tid & 3) * 4;
            const float4 val = *(const float4*)&cw[(size_t)(n0 + nl) * 768 + k0 + kl];
            Ws[kl + 0][nl] = val.x; Ws[kl + 1][nl] = val.y;
            Ws[kl + 2][nl] = val.z; Ws[kl + 3][nl] = val.w;
        }
        __syncthreads();
#pragma unroll
        for (int kk = 0; kk < BK; kk++) {
            float4 a0 = *(const float4*)&As[kk][ty * 8];
            float4 a1 = *(const float4*)&As[kk][ty * 8 + 4];
            float4 w0 = *(const float4*)&Ws[kk][tx * 4];
            float av[8] = {a0.x, a0.y, a0.z, a0.w, a1.x, a1.y, a1.z, a1.w};
            float wv[4] = {w0.x, w0.y, w0.z, w0.w};
#pragma unroll
            for (int i = 0; i < 8; i++)
#pragma unroll
                for (int j = 0; j < 4; j++) acc[i][j] += av[i] * wv[j];
        }
        __syncthreads();
    }
#pragma unroll
    for (int i = 0; i < 8; i++) {
        int m = m0 + ty * 8 + i;
        int b = m / 196, pp = m - b * 196;
        size_t row = (size_t)b * SEQ_ + 1 + pp;
#pragma unroll
        for (int j = 0; j < 4; j++) {
            int n = n0 + tx * 4 + j;
            x[row * DIM_ + n] = acc[i][j] + cb[n] + pos[(size_t)(1 + pp) * DIM_ + n];
        }
    }
}

// fp32 head GEMM (M=32, N=1000, K=768) — tiny.
__launch_bounds__(256)
__global__ void gemm_f32_bias(const float* __restrict__ A, const float* __restrict__ W,
                              const float* __restrict__ bias, float* __restrict__ C,
                              int M, int N, int K) {
    __shared__ __align__(16) float As[BK][BM + 4];
    __shared__ __align__(16) float Ws[BK][BN + 4];
    const int tid = threadIdx.x;
    const int tx = tid & 15, ty = tid >> 4;
    const int m0 = blockIdx.y * BM;
    const int n0 = blockIdx.x * BN;
    float acc[8][4];
#pragma unroll
    for (int i = 0; i < 8; i++)
#pragma unroll
        for (int j = 0; j < 4; j++) acc[i][j] = 0.f;

    for (int k0 = 0; k0 < K; k0 += BK) {
#pragma unroll
        for (int it = 0; it < 2; it++) {
            int e4 = tid + it * 256;
            int ml = e4 >> 2;
            int kl = (e4 & 3) * 4;
            int m = m0 + ml;
            float4 val = make_float4(0.f, 0.f, 0.f, 0.f);
            if (m < M) val = *(const float4*)&A[(size_t)m * K + k0 + kl];
            As[kl + 0][ml] = val.x; As[kl + 1][ml] = val.y;
            As[kl + 2][ml] = val.z; As[kl + 3][ml] = val.w;
        }
        {
            int nl = tid >> 2;
            int kl = (tid & 3) * 4;
            int n = n0 + nl;
            float4 val = make_float4(0.f, 0.f, 0.f, 0.f);
            if (n < N) val = *(const float4*)&W[(size_t)n * K + k0 + kl];
            Ws[kl + 0][nl] = val.x; Ws[kl + 1][nl] = val.y;
            Ws[kl + 2][nl] = val.z; Ws[kl + 3][nl] = val.w;
        }
        __syncthreads();
#pragma unroll
        for (int kk = 0; kk < BK; kk++) {
            float4 a0 = *(const float4*)&As[kk][ty * 8];
            float4 a1 = *(const float4*)&As[kk][ty * 8 + 4];
            float4 w0 = *(const float4*)&Ws[kk][tx * 4];
            float av[8] = {a0.x, a0.y, a0.z, a0.w, a1.x, a1.y, a1.z, a1.w};
            float wv[4] = {w0.x, w0.y, w0.z, w0.w};
#pragma unroll
            for (int i = 0; i < 8; i++)
#pragma unroll
                for (int j = 0; j < 4; j++) acc[i][j] += av[i] * wv[j];
        }
        __syncthreads();
    }
#pragma unroll
    for (int i = 0; i < 8; i++) {
        int m = m0 + ty * 8 + i;
        if (m >= M) continue;
#pragma unroll
        for (int j = 0; j < 4; j++) {
            int n = n0 + tx * 4 + j;
            if (n >= N) continue;
            C[(size_t)m * N + n] = acc[i][j] + bias[n];
        }
    }
}

__global__ void cls_init(const float* __restrict__ cls, const float* __restrict__ pos,
                         float* __restrict__ x) {
    int idx = blockIdx.x * 256 + threadIdx.x;
    if (idx >= B_ * DIM_) return;
    int b = idx / DIM_, d = idx - b * DIM_;
    x[(size_t)b * SEQ_ * DIM_ + d] = cls[d] + pos[d];
}

template <typename OT>
__global__ __launch_bounds__(256)
void layernorm(const float* __restrict__ in, const float* __restrict__ g,
               const float* __restrict__ bta, OT* __restrict__ out, int row_mul) {
    const float* xr = in + (size_t)blockIdx.x * row_mul * DIM_;
    OT* orow = out + (size_t)blockIdx.x * DIM_;
    int tid = threadIdx.x;
    float v0 = xr[tid], v1 = xr[tid + 256], v2 = xr[tid + 512];
    __shared__ float s1[256], s2[256];
    s1[tid] = v0 + v1 + v2;
    s2[tid] = v0 * v0 + v1 * v1 + v2 * v2;
    __syncthreads();
    for (int off = 128; off > 0; off >>= 1) {
        if (tid < off) { s1[tid] += s1[tid + off]; s2[tid] += s2[tid + off]; }
        __syncthreads();
    }
    float mean = s1[0] * (1.f / 768.f);
    float var = s2[0] * (1.f / 768.f) - mean * mean;
    float rstd = rsqrtf(var + 1e-6f);
#pragma unroll
    for (int c = 0; c < 3; c++) {
        int idx = tid + c * 256;
        float vv = (c == 0) ? v0 : (c == 1) ? v1 : v2;
        float val = (vv - mean) * rstd * g[idx] + bta[idx];
        if constexpr (sizeof(OT) == 2) orow[idx] = f2bf(val);
        else                           orow[idx] = val;
    }
}

// One-shot fp32 -> bf16 of all per-layer weights into packed [12][LW_] buffer.
__global__ __launch_bounds__(256)
void cvt_weights(const float* __restrict__ qkv, const float* __restrict__ ow,
                 const float* __restrict__ m1, const float* __restrict__ m2,
                 unsigned short* __restrict__ dst) {
    const int L = blockIdx.y;
    const size_t r = ((size_t)blockIdx.x * 256 + threadIdx.x) * 8;
    const float* src;
    if (r < WOFF_OUT)       src = qkv + (size_t)L * 1769472 + r;
    else if (r < WOFF_M1)   src = ow  + (size_t)L * 589824  + (r - WOFF_OUT);
    else if (r < WOFF_M2)   src = m1  + (size_t)L * 2359296 + (r - WOFF_M1);
    else                    src = m2  + (size_t)L * 2359296 + (r - WOFF_M2);
    float4 a = *(const float4*)src, b = *(const float4*)(src + 4);
    unsigned short o[8] = {f2bf(a.x), f2bf(a.y), f2bf(a.z), f2bf(a.w),
                           f2bf(b.x), f2bf(b.y), f2bf(b.z), f2bf(b.w)};
    *(uint4*)(dst + (size_t)L * LW_ + r) = *(uint4*)o;
}

__global__ __launch_bounds__(256)
void cvt_simple(const float* __restrict__ src, unsigned short* __restrict__ dst, int n) {
    int i = (blockIdx.x * 256 + threadIdx.x) * 8;
    if (i >= n) return;
    float4 a = *(const float4*)(src + i), b = *(const float4*)(src + i + 4);
    unsigned short o[8] = {f2bf(a.x), f2bf(a.y), f2bf(a.z), f2bf(a.w),
                           f2bf(b.x), f2bf(b.y), f2bf(b.z), f2bf(b.w)};
    *(uint4*)(dst + i) = *(uint4*)o;
}

extern "C" void kernel_launch(void* const* d_in, const int* in_sizes, int n_in,
                              void* d_out, int out_size, void* d_ws, size_t ws_size,
                              hipStream_t stream) {
    const float* img     = (const float*)d_in[0];
    const float* conv_w  = (const float*)d_in[1];
    const float* conv_b  = (const float*)d_in[2];
    const float* cls_tok = (const float*)d_in[3];
    const float* pos_emb = (const float*)d_in[4];
    const float* ln1_g   = (const float*)d_in[5];
    const float* ln1_b   = (const float*)d_in[6];
    const float* qkv_w   = (const float*)d_in[7];
    const float* qkv_b   = (const float*)d_in[8];
    const float* out_w   = (const float*)d_in[9];
    const float* out_b   = (const float*)d_in[10];
    const float* ln2_g   = (const float*)d_in[11];
    const float* ln2_b   = (const float*)d_in[12];
    const float* mlp_w1  = (const float*)d_in[13];
    const float* mlp_b1  = (const float*)d_in[14];
    const float* mlp_w2  = (const float*)d_in[15];
    const float* mlp_b2  = (const float*)d_in[16];
    const float* lnf_g   = (const float*)d_in[17];
    const float* lnf_b   = (const float*)d_in[18];
    const float* fc_w    = (const float*)d_in[19];
    const float* fc_b    = (const float*)d_in[20];
    float* out = (float*)d_out;

    char* p = (char*)d_ws;
    float* x = (float*)p;                      p += (size_t)MROWS * DIM_ * 4;
    unsigned short* h    = (unsigned short*)p; p += (size_t)MPAD * DIM_ * 2;
    unsigned short* qb   = (unsigned short*)p; p += (size_t)MROWS * DIM_ * 2;
    unsigned short* kb   = (unsigned short*)p; p += (size_t)MROWS * DIM_ * 2;
    unsigned short* vb   = (unsigned short*)p; p += (size_t)MROWS * DIM_ * 2;
    unsigned short* obuf = (unsigned short*)p; p += (size_t)MPAD * DIM_ * 2;
    unsigned short* mid  = (unsigned short*)p; p += (size_t)MPAD * MLP_ * 2;
    float* hcls = (float*)p;                   p += (size_t)B_ * DIM_ * 4;
    // tier-A extras (only touched if ws_size is large enough):
    unsigned short* imgb = (unsigned short*)p; p += (size_t)B_ * 3 * 224 * 224 * 2;
    unsigned short* cwb  = (unsigned short*)p; p += (size_t)DIM_ * DIM_ * 2;
    unsigned short* wall = (unsigned short*)p; p += (size_t)DEPTH_ * LW_ * 2;

    const bool full = ws_size >= 288178176ull;   // tier A: pre-converted bf16 weights
    dim3 blk(256);

    if (full) {
        cvt_simple<<<2352, blk, 0, stream>>>(img, imgb, B_ * 3 * 224 * 224);
        cvt_simple<<<288, blk, 0, stream>>>(conv_w, cwb, DIM_ * DIM_);
        cvt_weights<<<dim3(3456, DEPTH_), blk, 0, stream>>>(qkv_w, out_w, mlp_w1, mlp_w2, wall);
        patch_embed_mfma<<<dim3(6, 49), blk, 0, stream>>>(imgb, cwb, conv_b, pos_emb, x);
    } else {
        patch_embed<<<dim3(12, 49), blk, 0, stream>>>(img, conv_w, conv_b, pos_emb, x);
    }
    cls_init<<<(B_ * DIM_ + 255) / 256, blk, 0, stream>>>(cls_tok, pos_emb, x);

    const int MT = (MROWS + 127) / 128;   // 50
    for (int L = 0; L < DEPTH_; L++) {
        const unsigned short* wl = wall + (size_t)L * LW_;
        layernorm<unsigned short><<<MROWS, blk, 0, stream>>>(
            x, ln1_g + L * DIM_, ln1_b + L * DIM_, h, 1);
        if (full)
            gemm_bf16<EPI_QKV, true><<<dim3(3 * DIM_ / 128, MT), blk, 0, stream>>>(
                h, wl + WOFF_QKV, qkv_b + (size_t)L * 3 * DIM_,
                nullptr, nullptr, MROWS, 3 * DIM_, DIM_, qb, kb, vb);
        else
            gemm_bf16<EPI_QKV, false><<<dim3(3 * DIM_ / 128, MT), blk, 0, stream>>>(
                h, qkv_w + (size_t)L * 3 * DIM_ * DIM_, qkv_b + (size_t)L * 3 * DIM_,
                nullptr, nullptr, MROWS, 3 * DIM_, DIM_, qb, kb, vb);
        attention_mfma<<<dim3(B_ * HEADS_, 4), blk, 0, stream>>>(qb, kb, vb, obuf);
        if (full)
            gemm_bf16<EPI_RES, true><<<dim3(DIM_ / 128, MT), blk, 0, stream>>>(
                obuf, wl + WOFF_OUT, out_b + (size_t)L * DIM_,
                x, nullptr, MROWS, DIM_, DIM_, nullptr, nullptr, nullptr);
        else
            gemm_bf16<EPI_RES, false><<<dim3(DIM_ / 128, MT), blk, 0, stream>>>(
                obuf, out_w + (size_t)L * DIM_ * DIM_, out_b + (size_t)L * DIM_,
                x, nullptr, MROWS, DIM_, DIM_, nullptr, nullptr, nullptr);
        layernorm<unsigned short><<<MROWS, blk, 0, stream>>>(
            x, ln2_g + L * DIM_, ln2_b + L * DIM_, h, 1);
        if (full)
            gemm_bf16<EPI_GELU, true><<<dim3(MLP_ / 128, MT), blk, 0, stream>>>(
                h, wl + WOFF_M1, mlp_b1 + (size_t)L * MLP_,
                nullptr, mid, MROWS, MLP_, DIM_, nullptr, nullptr, nullptr);
        else
            gemm_bf16<EPI_GELU, false><<<dim3(MLP_ / 128, MT), blk, 0, stream>>>(
                h, mlp_w1 + (size_t)L * MLP_ * DIM_, mlp_b1 + (size_t)L * MLP_,
                nullptr, mid, MROWS, MLP_, DIM_, nullptr, nullptr, nullptr);
        if (full)
            gemm_bf16<EPI_RES, true><<<dim3(DIM_ / 128, MT), blk, 0, stream>>>(
                mid, wl + WOFF_M2, mlp_b2 + (size_t)L * DIM_,
                x, nullptr, MROWS, DIM_, MLP_, nullptr, nullptr, nullptr);
        else
            gemm_bf16<EPI_RES, false><<<dim3(DIM_ / 128, MT), blk, 0, stream>>>(
                mid, mlp_w2 + (size_t)L * DIM_ * MLP_, mlp_b2 + (size_t)L * DIM_,
                x, nullptr, MROWS, DIM_, MLP_, nullptr, nullptr, nullptr);
    }
    layernorm<float><<<B_, blk, 0, stream>>>(x, lnf_g, lnf_b, hcls, SEQ_);
    gemm_f32_bias<<<dim3((NCLS_ + BN - 1) / BN, 1), blk, 0, stream>>>(
        hcls, fc_w, fc_b, out, B_, NCLS_, DIM_);
}

// Round 4
// 3320.282 us; speedup vs baseline: 8.2226x; 1.1727x over previous
//
#include <hip/hip_runtime.h>
#include <math.h>

#define B_     32
#define SEQ_   197
#define DIM_   768
#define HEADS_ 12
#define HD_    64
#define MLP_   3072
#define NCLS_  1000
#define DEPTH_ 12
#define MROWS  (B_ * SEQ_)   // 6304
#define MPAD   6400          // padded rows so MFMA A-tile reads never leave our buffers

// per-layer bf16 weight pack: [qkv 2304x768][out 768x768][mlp1 3072x768][mlp2 768x3072]
#define WOFF_QKV 0
#define WOFF_OUT 1769472
#define WOFF_M1  2359296
#define WOFF_M2  4718592
#define LW_      7077888

typedef short s8v __attribute__((ext_vector_type(8)));
typedef float f4v __attribute__((ext_vector_type(4)));

__device__ __forceinline__ unsigned short f2bf(float f) {
    union { float f; unsigned u; } v; v.f = f;
    unsigned r = v.u + 0x7FFFu + ((v.u >> 16) & 1u);   // RNE; inputs finite
    return (unsigned short)(r >> 16);
}
__device__ __forceinline__ float bf2f(unsigned short h) {
    union { unsigned u; float f; } v; v.u = ((unsigned)h) << 16; return v.f;
}
__device__ __forceinline__ void async16(const void* g, void* l) {
    __builtin_amdgcn_global_load_lds(
        (const __attribute__((address_space(1))) void*)g,
        (__attribute__((address_space(3))) void*)l, 16, 0, 0);
}

enum { EPI_QKV = 0, EPI_RES = 1, EPI_GELU = 2 };

// C = A(bf16)[M][K] . W[N][K]^T + bias, fused epilogue. Tile = (32*FM) x (32*FN);
// 4 waves in 2x2 grid, wave tile (16*FM) x (16*FN). WB: W already bf16 (async16
// staging); else fp32 W converted during staging (fallback tier).
// LDS: row = 8 chunks of 16B; chunk j stored at slot j^(row&7) (XOR swizzle).
template <int EPI, bool WB, int FM, int FN>
__global__ __launch_bounds__(256)
void gemm_bf16(const unsigned short* __restrict__ A, const void* __restrict__ Wv,
               const float* __restrict__ bias, float* __restrict__ X,
               unsigned short* __restrict__ O, int M, int N, int K,
               unsigned short* __restrict__ qo, unsigned short* __restrict__ ko,
               unsigned short* __restrict__ vo) {
    __shared__ __align__(16) unsigned short As[32 * FM * 64];
    __shared__ __align__(16) unsigned short Bs[32 * FN * 64];
    const int tid = threadIdx.x;
    const int m0 = blockIdx.y * (32 * FM), n0 = blockIdx.x * (32 * FN);
    const int w = tid >> 6, lane = tid & 63;
    const int wm = w & 1, wn = w >> 1;
    const int qd = lane >> 4, mr = lane & 15;

    f4v acc[FM][FN] = {};

    for (int k0 = 0; k0 < K; k0 += 64) {
#pragma unroll
        for (int r = 0; r < FM; r++) {
            int c = r * 256 + tid;
            int m = c >> 3, slot = c & 7;
            int j = slot ^ (m & 7);
            async16(A + (size_t)(m0 + m) * K + k0 + j * 8, (char*)As + c * 16);
        }
        if constexpr (WB) {
            const unsigned short* Wb = (const unsigned short*)Wv;
#pragma unroll
            for (int r = 0; r < FN; r++) {
                int c = r * 256 + tid;
                int n = c >> 3, slot = c & 7;
                int j = slot ^ (n & 7);
                async16(Wb + (size_t)(n0 + n) * K + k0 + j * 8, (char*)Bs + c * 16);
            }
        } else {
            const float* Wf = (const float*)Wv;
#pragma unroll
            for (int r = 0; r < 2 * FN; r++) {
                int u = r * 256 + tid;
                int n = u >> 4, kq = (u & 15) * 4;
                const float4 wv = *(const float4*)&Wf[(size_t)(n0 + n) * K + k0 + kq];
                int off = n * 128 + (((kq >> 3) ^ (n & 7)) << 4) + (kq & 7) * 2;
                unsigned p0 = (unsigned)f2bf(wv.x) | ((unsigned)f2bf(wv.y) << 16);
                unsigned p1 = (unsigned)f2bf(wv.z) | ((unsigned)f2bf(wv.w) << 16);
                *(uint2*)((char*)Bs + off) = make_uint2(p0, p1);
            }
        }
        __syncthreads();
#pragma unroll
        for (int s = 0; s < 2; s++) {
            s8v a[FM], b[FN];
            const int j = s * 4 + qd;
#pragma unroll
            for (int i = 0; i < FM; i++) {
                int ml = wm * 16 * FM + i * 16 + mr;
                a[i] = *(const s8v*)((const char*)As + ml * 128 + ((j ^ (ml & 7)) << 4));
            }
#pragma unroll
            for (int i = 0; i < FN; i++) {
                int nl = wn * 16 * FN + i * 16 + mr;
                b[i] = *(const s8v*)((const char*)Bs + nl * 128 + ((j ^ (nl & 7)) << 4));
            }
#pragma unroll
            for (int i = 0; i < FM; i++)
#pragma unroll
                for (int jj = 0; jj < FN; jj++)
                    acc[i][jj] = __builtin_amdgcn_mfma_f32_16x16x32_bf16(
                        a[i], b[jj], acc[i][jj], 0, 0, 0);
        }
        __syncthreads();
    }

    // C/D layout: col = lane&15, row = (lane>>4)*4 + reg.
#pragma unroll
    for (int i = 0; i < FM; i++) {
#pragma unroll
        for (int jj = 0; jj < FN; jj++) {
            const int n = n0 + wn * 16 * FN + jj * 16 + mr;
            const float bn = bias[n];
#pragma unroll
            for (int r = 0; r < 4; r++) {
                const int m = m0 + wm * 16 * FM + i * 16 + qd * 4 + r;
                if (m >= M) continue;
                float val = acc[i][jj][r] + bn;
                if constexpr (EPI == EPI_RES) {
                    X[(size_t)m * N + n] += val;   // fp32 residual accumulate
                } else if constexpr (EPI == EPI_GELU) {
                    O[(size_t)m * N + n] =
                        f2bf(0.5f * val * (1.f + erff(val * 0.70710678118654752f)));
                } else {  // EPI_QKV: scatter to [B][HEADS][SEQ][HD] bf16; q pre-scaled
                    int b = m / SEQ_, s = m - b * SEQ_;
                    int i3 = n / DIM_, nr = n - i3 * DIM_;
                    int hh = nr >> 6, d = nr & 63;
                    if (i3 == 0) val *= 0.125f;    // fold 1/sqrt(HD) into q
                    unsigned short* dst = (i3 == 0) ? qo : (i3 == 1) ? ko : vo;
                    dst[(((size_t)(b * HEADS_ + hh)) * SEQ_ + s) * HD_ + d] = f2bf(val);
                }
            }
        }
    }
}

// MFMA attention. grid(B*H, 4): 64 query rows per block, 16 per wave.
// LDS reuse: KV region holds K[208][72] for QK^T, then V^T[64][256] (XOR-swizzled)
// for PV. q arrives pre-scaled by 1/8.
__global__ __launch_bounds__(256)
void attention_mfma(const unsigned short* __restrict__ q, const unsigned short* __restrict__ k,
                    const unsigned short* __restrict__ v, unsigned short* __restrict__ ob) {
    __shared__ __align__(16) char smem[62464];
    unsigned short* KV = (unsigned short*)smem;            // max(29952, 32768) B
    unsigned short* P  = (unsigned short*)(smem + 32768);  // 4 waves x [16][232] bf16
    const int bh = blockIdx.x, sblk = blockIdx.y;
    const int bi = bh / HEADS_, hh = bh - bi * HEADS_;
    const unsigned short* qp = q + (size_t)bh * SEQ_ * HD_;
    const unsigned short* kp = k + (size_t)bh * SEQ_ * HD_;
    const unsigned short* vp = v + (size_t)bh * SEQ_ * HD_;
    unsigned short* op = ob + (size_t)bi * SEQ_ * DIM_ + hh * HD_;
    const int tid = threadIdx.x;
    const int w = tid >> 6, lane = tid & 63;
    const int mq = lane & 15, quad = lane >> 4;

    // stage K[197][64] -> rows stride 72 (2-way-free banks); zero rows 197..207
    for (int c = tid; c < 197 * 8; c += 256) {
        int t = c >> 3, ch = c & 7;
        *(uint4*)(KV + t * 72 + ch * 8) = *(const uint4*)(kp + c * 8);
    }
    if (tid < 88) {
        int t = 197 + (tid >> 3), ch = tid & 7;
        *(uint4*)(KV + t * 72 + ch * 8) = make_uint4(0, 0, 0, 0);
    }
    // Q A-frags straight from global: A[m=lane&15][k=quad*8+j]
    const int sA = sblk * 64 + w * 16 + mq;   // may exceed 196: reads stay inside ws
    s8v a0 = *(const s8v*)(qp + sA * 64 + quad * 8);
    s8v a1 = *(const s8v*)(qp + sA * 64 + 32 + quad * 8);
    __syncthreads();

    f4v acc[13] = {};
#pragma unroll
    for (int ti = 0; ti < 13; ti++) {
        const unsigned short* kr = KV + (ti * 16 + mq) * 72 + quad * 8;
        s8v b0 = *(const s8v*)kr;
        s8v b1 = *(const s8v*)(kr + 32);
        acc[ti] = __builtin_amdgcn_mfma_f32_16x16x32_bf16(a0, b0, acc[ti], 0, 0, 0);
        acc[ti] = __builtin_amdgcn_mfma_f32_16x16x32_bf16(a1, b1, acc[ti], 0, 0, 0);
    }
    // row softmax in-register; rows = quad*4+r, cols = ti*16+mq
    float mxr[4] = {-3e38f, -3e38f, -3e38f, -3e38f};
#pragma unroll
    for (int ti = 0; ti < 13; ti++) {
        const bool msk = (ti == 12) && (mq >= 5);   // t >= 197
#pragma unroll
        for (int r = 0; r < 4; r++) {
            float vs = msk ? -3e38f : acc[ti][r];
            acc[ti][r] = vs;
            mxr[r] = fmaxf(mxr[r], vs);
        }
    }
#pragma unroll
    for (int r = 0; r < 4; r++)
#pragma unroll
        for (int off = 1; off < 16; off <<= 1)
            mxr[r] = fmaxf(mxr[r], __shfl_xor(mxr[r], off));
    float sum[4] = {0.f, 0.f, 0.f, 0.f};
#pragma unroll
    for (int ti = 0; ti < 13; ti++)
#pragma unroll
        for (int r = 0; r < 4; r++) {
            float e = __expf(acc[ti][r] - mxr[r]);
            acc[ti][r] = e;
            sum[r] += e;
        }
#pragma unroll
    for (int r = 0; r < 4; r++) {
#pragma unroll
        for (int off = 1; off < 16; off <<= 1) sum[r] += __shfl_xor(sum[r], off);
        sum[r] = 1.f / sum[r];
    }
    unsigned short* Pw = P + w * 16 * 232;   // wave-private: no barrier needed
#pragma unroll
    for (int ti = 0; ti < 13; ti++)
#pragma unroll
        for (int r = 0; r < 4; r++)
            Pw[(quad * 4 + r) * 232 + ti * 16 + mq] = f2bf(acc[ti][r] * sum[r]);
    {   // zero P cols 208..223 (PV K-pad)
        int r2 = lane >> 2, c2 = 208 + (lane & 3) * 4;
        *(uint2*)(Pw + r2 * 232 + c2) = make_uint2(0, 0);
    }
    __syncthreads();   // all waves done reading K
    // stage V^T[64 d][256 t], 16B-chunk XOR swizzle: chunk' = chunk ^ (d&7) ^ ((d>>3)&7).
    // Register transpose: 4x uint4 loads -> 8x conflict-free ds_write_b64.
#pragma unroll
    for (int pass = 0; pass < 2; pass++) {
        int u = pass * 256 + tid;       // 0..511
        int o = u & 7;                  // d-octet
        int tq = u >> 3;                // t-quad 0..63
        uint4 rv[4];
#pragma unroll
        for (int tt = 0; tt < 4; tt++) {
            int t = tq * 4 + tt;
            rv[tt] = (t < SEQ_) ? *(const uint4*)(vp + t * 64 + o * 8)
                                : make_uint4(0, 0, 0, 0);
        }
#pragma unroll
        for (int i = 0; i < 8; i++) {
            int d = o * 8 + i;
            int cs = (tq >> 1) ^ i ^ o;   // (d&7)=i, ((d>>3)&7)=o
            unsigned short p0 = ((const unsigned short*)&rv[0])[i];
            unsigned short p1 = ((const unsigned short*)&rv[1])[i];
            unsigned short p2 = ((const unsigned short*)&rv[2])[i];
            unsigned short p3 = ((const unsigned short*)&rv[3])[i];
            uint2 w2 = make_uint2((unsigned)p0 | ((unsigned)p1 << 16),
                                  (unsigned)p2 | ((unsigned)p3 << 16));
            *(uint2*)((char*)KV + d * 512 + cs * 16 + (tq & 1) * 8) = w2;
        }
    }
    __syncthreads();
    f4v po[4] = {};
#pragma unroll
    for (int kt = 0; kt < 7; kt++) {
        s8v pa = *(const s8v*)(Pw + mq * 232 + kt * 32 + quad * 8);
#pragma unroll
        for (int nt = 0; nt < 4; nt++) {
            int d = nt * 16 + mq;
            int cs = (kt * 4 + quad) ^ (d & 7) ^ ((d >> 3) & 7);
            s8v vb2 = *(const s8v*)((const char*)KV + d * 512 + cs * 16);
            po[nt] = __builtin_amdgcn_mfma_f32_16x16x32_bf16(pa, vb2, po[nt], 0, 0, 0);
        }
    }
#pragma unroll
    for (int nt = 0; nt < 4; nt++)
#pragma unroll
        for (int r = 0; r < 4; r++) {
            int s = sblk * 64 + w * 16 + quad * 4 + r;
            if (s < SEQ_) op[(size_t)s * DIM_ + nt * 16 + mq] = f2bf(po[nt][r]);
        }
}

// Patch embedding as bf16 MFMA GEMM: M=6272 (b,gh,gw), N=768, K=768 (c,r,q).
__global__ __launch_bounds__(256)
void patch_embed_mfma(const unsigned short* __restrict__ imgb,
                      const unsigned short* __restrict__ cwb,
                      const float* __restrict__ cb, const float* __restrict__ pos,
                      float* __restrict__ x) {
    __shared__ __align__(16) unsigned short As[128 * 64];
    __shared__ __align__(16) unsigned short Bs[128 * 64];
    const int tid = threadIdx.x;
    const int m0 = blockIdx.y * 128, n0 = blockIdx.x * 128;
    const int w = tid >> 6, lane = tid & 63;
    const int wm = w & 1, wn = w >> 1;
    const int qd = lane >> 4, mr = lane & 15;

    int rowoff[4], jj4[4];
#pragma unroll
    for (int r = 0; r < 4; r++) {
        int c = r * 256 + tid;
        int m = c >> 3, slot = c & 7;
        jj4[r] = slot ^ (m & 7);
        int mg = m0 + m;
        int b = mg / 196, pp = mg - b * 196;
        int gh = pp / 14, gw = pp - gh * 14;
        rowoff[r] = ((b * 3) * 224 + gh * 16) * 224 + gw * 16;
    }
    f4v acc[4][4] = {};
    for (int k0 = 0; k0 < 768; k0 += 64) {
#pragma unroll
        for (int r = 0; r < 4; r++) {
            int c = r * 256 + tid;
            int kb = k0 + jj4[r] * 8;
            int cc = kb >> 8, rr = (kb >> 4) & 15, qh = kb & 15;
            async16(imgb + rowoff[r] + (cc * 224 + rr) * 224 + qh, (char*)As + c * 16);
        }
#pragma unroll
        for (int r = 0; r < 4; r++) {
            int c = r * 256 + tid;
            int n = c >> 3, slot = c & 7;
            int j = slot ^ (n & 7);
            async16(cwb + (size_t)(n0 + n) * 768 + k0 + j * 8, (char*)Bs + c * 16);
        }
        __syncthreads();
#pragma unroll
        for (int s = 0; s < 2; s++) {
            s8v a[4], b[4];
            const int j = s * 4 + qd;
#pragma unroll
            for (int i = 0; i < 4; i++) {
                int ml = wm * 64 + i * 16 + mr;
                a[i] = *(const s8v*)((const char*)As + ml * 128 + ((j ^ (ml & 7)) << 4));
                int nl = wn * 64 + i * 16 + mr;
                b[i] = *(const s8v*)((const char*)Bs + nl * 128 + ((j ^ (nl & 7)) << 4));
            }
#pragma unroll
            for (int i = 0; i < 4; i++)
#pragma unroll
                for (int jj = 0; jj < 4; jj++)
                    acc[i][jj] = __builtin_amdgcn_mfma_f32_16x16x32_bf16(
                        a[i], b[jj], acc[i][jj], 0, 0, 0);
        }
        __syncthreads();
    }
#pragma unroll
    for (int i = 0; i < 4; i++)
#pragma unroll
        for (int jj = 0; jj < 4; jj++) {
            const int n = n0 + wn * 64 + jj * 16 + mr;
            const float bn = cb[n];
#pragma unroll
            for (int r = 0; r < 4; r++) {
                const int m = m0 + wm * 64 + i * 16 + qd * 4 + r;
                int b = m / 196, pp = m - b * 196;
                x[((size_t)(b * 197 + 1 + pp)) * 768 + n] =
                    acc[i][jj][r] + bn + pos[(size_t)(1 + pp) * 768 + n];
            }
        }
}

// fp32 patch embed fallback (tier C) — round-1 kernel.
#define BM 128
#define BN 64
#define BK 16
__launch_bounds__(256)
__global__ void patch_embed(const float* __restrict__ img, const float* __restrict__ cw,
                            const float* __restrict__ cb, const float* __restrict__ pos,
                            float* __restrict__ x) {
    __shared__ __align__(16) float As[BK][BM + 4];
    __shared__ __align__(16) float Ws[BK][BN + 4];
    const int tid = threadIdx.x;
    const int tx = tid & 15, ty = tid >> 4;
    const int m0 = blockIdx.y * BM;
    const int n0 = blockIdx.x * BN;
    float acc[8][4];
#pragma unroll
    for (int i = 0; i < 8; i++)
#pragma unroll
        for (int j = 0; j < 4; j++) acc[i][j] = 0.f;

    for (int k0 = 0; k0 < 768; k0 += BK) {
#pragma unroll
        for (int it = 0; it < 2; it++) {
            int e4 = tid + it * 256;
            int ml = e4 >> 2;
            int kl = (e4 & 3) * 4;
            int m = m0 + ml;
            int b = m / 196, pp = m - b * 196;
            int gh = pp / 14, gw = pp - gh * 14;
            int k = k0 + kl;
            int c = k >> 8, r = (k >> 4) & 15, qq = k & 15;
            const float4 val = *(const float4*)
                &img[(((size_t)(b * 3 + c) * 224) + gh * 16 + r) * 224 + gw * 16 + qq];
            As[kl + 0][ml] = val.x; As[kl + 1][ml] = val.y;
            As[kl + 2][ml] = val.z; As[kl + 3][ml] = val.w;
        }
        {
            int nl = tid >> 2;
            int kl = (tid & 3) * 4;
            const float4 val = *(const float4*)&cw[(size_t)(n0 + nl) * 768 + k0 + kl];
            Ws[kl + 0][nl] = val.x; Ws[kl + 1][nl] = val.y;
            Ws[kl + 2][nl] = val.z; Ws[kl + 3][nl] = val.w;
        }
        __syncthreads();
#pragma unroll
        for (int kk = 0; kk < BK; kk++) {
            float4 a0 = *(const float4*)&As[kk][ty * 8];
            float4 a1 = *(const float4*)&As[kk][ty * 8 + 4];
            float4 w0 = *(const float4*)&Ws[kk][tx * 4];
            float av[8] = {a0.x, a0.y, a0.z, a0.w, a1.x, a1.y, a1.z, a1.w};
            float wv[4] = {w0.x, w0.y, w0.z, w0.w};
#pragma unroll
            for (int i = 0; i < 8; i++)
#pragma unroll
                for (int j = 0; j < 4; j++) acc[i][j] += av[i] * wv[j];
        }
        __syncthreads();
    }
#pragma unroll
    for (int i = 0; i < 8; i++) {
        int m = m0 + ty * 8 + i;
        int b = m / 196, pp = m - b * 196;
        size_t row = (size_t)b * SEQ_ + 1 + pp;
#pragma unroll
        for (int j = 0; j < 4; j++) {
            int n = n0 + tx * 4 + j;
            x[row * DIM_ + n] = acc[i][j] + cb[n] + pos[(size_t)(1 + pp) * DIM_ + n];
        }
    }
}

// fp32 head GEMM (M=32, N=1000, K=768) — tiny.
__launch_bounds__(256)
__global__ void gemm_f32_bias(const float* __restrict__ A, const float* __restrict__ W,
                              const float* __restrict__ bias, float* __restrict__ C,
                              int M, int N, int K) {
    __shared__ __align__(16) float As[BK][BM + 4];
    __shared__ __align__(16) float Ws[BK][BN + 4];
    const int tid = threadIdx.x;
    const int tx = tid & 15, ty = tid >> 4;
    const int m0 = blockIdx.y * BM;
    const int n0 = blockIdx.x * BN;
    float acc[8][4];
#pragma unroll
    for (int i = 0; i < 8; i++)
#pragma unroll
        for (int j = 0; j < 4; j++) acc[i][j] = 0.f;

    for (int k0 = 0; k0 < K; k0 += BK) {
#pragma unroll
        for (int it = 0; it < 2; it++) {
            int e4 = tid + it * 256;
            int ml = e4 >> 2;
            int kl = (e4 & 3) * 4;
            int m = m0 + ml;
            float4 val = make_float4(0.f, 0.f, 0.f, 0.f);
            if (m < M) val = *(const float4*)&A[(size_t)m * K + k0 + kl];
            As[kl + 0][ml] = val.x; As[kl + 1][ml] = val.y;
            As[kl + 2][ml] = val.z; As[kl + 3][ml] = val.w;
        }
        {
            int nl = tid >> 2;
            int kl = (tid & 3) * 4;
            int n = n0 + nl;
            float4 val = make_float4(0.f, 0.f, 0.f, 0.f);
            if (n < N) val = *(const float4*)&W[(size_t)n * K + k0 + kl];
            Ws[kl + 0][nl] = val.x; Ws[kl + 1][nl] = val.y;
            Ws[kl + 2][nl] = val.z; Ws[kl + 3][nl] = val.w;
        }
        __syncthreads();
#pragma unroll
        for (int kk = 0; kk < BK; kk++) {
            float4 a0 = *(const float4*)&As[kk][ty * 8];
            float4 a1 = *(const float4*)&As[kk][ty * 8 + 4];
            float4 w0 = *(const float4*)&Ws[kk][tx * 4];
            float av[8] = {a0.x, a0.y, a0.z, a0.w, a1.x, a1.y, a1.z, a1.w};
            float wv[4] = {w0.x, w0.y, w0.z, w0.w};
#pragma unroll
            for (int i = 0; i < 8; i++)
#pragma unroll
                for (int j = 0; j < 4; j++) acc[i][j] += av[i] * wv[j];
        }
        __syncthreads();
    }
#pragma unroll
    for (int i = 0; i < 8; i++) {
        int m = m0 + ty * 8 + i;
        if (m >= M) continue;
#pragma unroll
        for (int j = 0; j < 4; j++) {
            int n = n0 + tx * 4 + j;
            if (n >= N) continue;
            C[(size_t)m * N + n] = acc[i][j] + bias[n];
        }
    }
}

__global__ void cls_init(const float* __restrict__ cls, const float* __restrict__ pos,
                         float* __restrict__ x) {
    int idx = blockIdx.x * 256 + threadIdx.x;
    if (idx >= B_ * DIM_) return;
    int b = idx / DIM_, d = idx - b * DIM_;
    x[(size_t)b * SEQ_ * DIM_ + d] = cls[d] + pos[d];
}

// Wave-per-row LayerNorm: 4 rows/block, shuffle-only reduction, no barriers.
template <typename OT>
__global__ __launch_bounds__(256)
void layernorm_w(const float* __restrict__ in, const float* __restrict__ g,
                 const float* __restrict__ bta, OT* __restrict__ out,
                 int rows, int row_mul) {
    const int w = threadIdx.x >> 6, lane = threadIdx.x & 63;
    const int row = blockIdx.x * 4 + w;
    if (row >= rows) return;
    const float* xr = in + (size_t)row * row_mul * DIM_;
    float4 v[3];
    float s = 0.f, s2 = 0.f;
#pragma unroll
    for (int j = 0; j < 3; j++) {
        v[j] = *(const float4*)&xr[lane * 4 + j * 256];
        s  += v[j].x + v[j].y + v[j].z + v[j].w;
        s2 += v[j].x * v[j].x + v[j].y * v[j].y + v[j].z * v[j].z + v[j].w * v[j].w;
    }
#pragma unroll
    for (int off = 32; off > 0; off >>= 1) {
        s += __shfl_xor(s, off);
        s2 += __shfl_xor(s2, off);
    }
    const float mean = s * (1.f / 768.f);
    const float var = s2 * (1.f / 768.f) - mean * mean;
    const float rstd = rsqrtf(var + 1e-6f);
    OT* orow = out + (size_t)row * DIM_;
#pragma unroll
    for (int j = 0; j < 3; j++) {
        const int c = lane * 4 + j * 256;
        const float4 gv = *(const float4*)&g[c];
        const float4 bv = *(const float4*)&bta[c];
        float r0 = (v[j].x - mean) * rstd * gv.x + bv.x;
        float r1 = (v[j].y - mean) * rstd * gv.y + bv.y;
        float r2 = (v[j].z - mean) * rstd * gv.z + bv.z;
        float r3 = (v[j].w - mean) * rstd * gv.w + bv.w;
        if constexpr (sizeof(OT) == 2) {
            unsigned short pk[4] = {f2bf(r0), f2bf(r1), f2bf(r2), f2bf(r3)};
            *(uint2*)&orow[c] = *(const uint2*)pk;
        } else {
            *(float4*)&orow[c] = make_float4(r0, r1, r2, r3);
        }
    }
}

// One-shot fp32 -> bf16 of all per-layer weights into packed [12][LW_] buffer.
__global__ __launch_bounds__(256)
void cvt_weights(const float* __restrict__ qkv, const float* __restrict__ ow,
                 const float* __restrict__ m1, const float* __restrict__ m2,
                 unsigned short* __restrict__ dst) {
    const int L = blockIdx.y;
    const size_t r = ((size_t)blockIdx.x * 256 + threadIdx.x) * 8;
    const float* src;
    if (r < WOFF_OUT)       src = qkv + (size_t)L * 1769472 + r;
    else if (r < WOFF_M1)   src = ow  + (size_t)L * 589824  + (r - WOFF_OUT);
    else if (r < WOFF_M2)   src = m1  + (size_t)L * 2359296 + (r - WOFF_M1);
    else                    src = m2  + (size_t)L * 2359296 + (r - WOFF_M2);
    float4 a = *(const float4*)src, b = *(const float4*)(src + 4);
    unsigned short o[8] = {f2bf(a.x), f2bf(a.y), f2bf(a.z), f2bf(a.w),
                           f2bf(b.x), f2bf(b.y), f2bf(b.z), f2bf(b.w)};
    *(uint4*)(dst + (size_t)L * LW_ + r) = *(uint4*)o;
}

__global__ __launch_bounds__(256)
void cvt_simple(const float* __restrict__ src, unsigned short* __restrict__ dst, int n) {
    int i = (blockIdx.x * 256 + threadIdx.x) * 8;
    if (i >= n) return;
    float4 a = *(const float4*)(src + i), b = *(const float4*)(src + i + 4);
    unsigned short o[8] = {f2bf(a.x), f2bf(a.y), f2bf(a.z), f2bf(a.w),
                           f2bf(b.x), f2bf(b.y), f2bf(b.z), f2bf(b.w)};
    *(uint4*)(dst + i) = *(uint4*)o;
}

extern "C" void kernel_launch(void* const* d_in, const int* in_sizes, int n_in,
                              void* d_out, int out_size, void* d_ws, size_t ws_size,
                              hipStream_t stream) {
    const float* img     = (const float*)d_in[0];
    const float* conv_w  = (const float*)d_in[1];
    const float* conv_b  = (const float*)d_in[2];
    const float* cls_tok = (const float*)d_in[3];
    const float* pos_emb = (const float*)d_in[4];
    const float* ln1_g   = (const float*)d_in[5];
    const float* ln1_b   = (const float*)d_in[6];
    const float* qkv_w   = (const float*)d_in[7];
    const float* qkv_b   = (const float*)d_in[8];
    const float* out_w   = (const float*)d_in[9];
    const float* out_b   = (const float*)d_in[10];
    const float* ln2_g   = (const float*)d_in[11];
    const float* ln2_b   = (const float*)d_in[12];
    const float* mlp_w1  = (const float*)d_in[13];
    const float* mlp_b1  = (const float*)d_in[14];
    const float* mlp_w2  = (const float*)d_in[15];
    const float* mlp_b2  = (const float*)d_in[16];
    const float* lnf_g   = (const float*)d_in[17];
    const float* lnf_b   = (const float*)d_in[18];
    const float* fc_w    = (const float*)d_in[19];
    const float* fc_b    = (const float*)d_in[20];
    float* out = (float*)d_out;

    char* p = (char*)d_ws;
    float* x = (float*)p;                      p += (size_t)MROWS * DIM_ * 4;
    unsigned short* h    = (unsigned short*)p; p += (size_t)MPAD * DIM_ * 2;
    unsigned short* qb   = (unsigned short*)p; p += (size_t)MROWS * DIM_ * 2;
    unsigned short* kb   = (unsigned short*)p; p += (size_t)MROWS * DIM_ * 2;
    unsigned short* vb   = (unsigned short*)p; p += (size_t)MROWS * DIM_ * 2;
    unsigned short* obuf = (unsigned short*)p; p += (size_t)MPAD * DIM_ * 2;
    unsigned short* mid  = (unsigned short*)p; p += (size_t)MPAD * MLP_ * 2;
    float* hcls = (float*)p;                   p += (size_t)B_ * DIM_ * 4;
    // tier-A extras (only touched if ws_size is large enough):
    unsigned short* imgb = (unsigned short*)p; p += (size_t)B_ * 3 * 224 * 224 * 2;
    unsigned short* cwb  = (unsigned short*)p; p += (size_t)DIM_ * DIM_ * 2;
    unsigned short* wall = (unsigned short*)p; p += (size_t)DEPTH_ * LW_ * 2;

    const bool full = ws_size >= 288178176ull;   // tier A: pre-converted bf16 weights
    dim3 blk(256);

    if (full) {
        cvt_simple<<<2352, blk, 0, stream>>>(img, imgb, B_ * 3 * 224 * 224);
        cvt_simple<<<288, blk, 0, stream>>>(conv_w, cwb, DIM_ * DIM_);
        cvt_weights<<<dim3(3456, DEPTH_), blk, 0, stream>>>(qkv_w, out_w, mlp_w1, mlp_w2, wall);
        patch_embed_mfma<<<dim3(6, 49), blk, 0, stream>>>(imgb, cwb, conv_b, pos_emb, x);
    } else {
        patch_embed<<<dim3(12, 49), blk, 0, stream>>>(img, conv_w, conv_b, pos_emb, x);
    }
    cls_init<<<(B_ * DIM_ + 255) / 256, blk, 0, stream>>>(cls_tok, pos_emb, x);

    const int MT  = (MROWS + 127) / 128;   // 50  (FM=4 tiles)
    const int MT2 = (MROWS + 63) / 64;     // 99  (FM=2 tiles)
    const int LNB = (MROWS + 3) / 4;       // 1576
    for (int L = 0; L < DEPTH_; L++) {
        const unsigned short* wl = wall + (size_t)L * LW_;
        layernorm_w<unsigned short><<<LNB, blk, 0, stream>>>(
            x, ln1_g + L * DIM_, ln1_b + L * DIM_, h, MROWS, 1);
        if (full)
            gemm_bf16<EPI_QKV, true, 4, 4><<<dim3(18, MT), blk, 0, stream>>>(
                h, wl + WOFF_QKV, qkv_b + (size_t)L * 3 * DIM_,
                nullptr, nullptr, MROWS, 3 * DIM_, DIM_, qb, kb, vb);
        else
            gemm_bf16<EPI_QKV, false, 4, 4><<<dim3(18, MT), blk, 0, stream>>>(
                h, qkv_w + (size_t)L * 3 * DIM_ * DIM_, qkv_b + (size_t)L * 3 * DIM_,
                nullptr, nullptr, MROWS, 3 * DIM_, DIM_, qb, kb, vb);
        attention_mfma<<<dim3(B_ * HEADS_, 4), blk, 0, stream>>>(qb, kb, vb, obuf);
        if (full)
            gemm_bf16<EPI_RES, true, 2, 4><<<dim3(6, MT2), blk, 0, stream>>>(
                obuf, wl + WOFF_OUT, out_b + (size_t)L * DIM_,
                x, nullptr, MROWS, DIM_, DIM_, nullptr, nullptr, nullptr);
        else
            gemm_bf16<EPI_RES, false, 2, 4><<<dim3(6, MT2), blk, 0, stream>>>(
                obuf, out_w + (size_t)L * DIM_ * DIM_, out_b + (size_t)L * DIM_,
                x, nullptr, MROWS, DIM_, DIM_, nullptr, nullptr, nullptr);
        layernorm_w<unsigned short><<<LNB, blk, 0, stream>>>(
            x, ln2_g + L * DIM_, ln2_b + L * DIM_, h, MROWS, 1);
        if (full)
            gemm_bf16<EPI_GELU, true, 4, 4><<<dim3(24, MT), blk, 0, stream>>>(
                h, wl + WOFF_M1, mlp_b1 + (size_t)L * MLP_,
                nullptr, mid, MROWS, MLP_, DIM_, nullptr, nullptr, nullptr);
        else
            gemm_bf16<EPI_GELU, false, 4, 4><<<dim3(24, MT), blk, 0, stream>>>(
                h, mlp_w1 + (size_t)L * MLP_ * DIM_, mlp_b1 + (size_t)L * MLP_,
                nullptr, mid, MROWS, MLP_, DIM_, nullptr, nullptr, nullptr);
        if (full)
            gemm_bf16<EPI_RES, true, 2, 4><<<dim3(6, MT2), blk, 0, stream>>>(
                mid, wl + WOFF_M2, mlp_b2 + (size_t)L * DIM_,
                x, nullptr, MROWS, DIM_, MLP_, nullptr, nullptr, nullptr);
        else
            gemm_bf16<EPI_RES, false, 2, 4><<<dim3(6, MT2), blk, 0, stream>>>(
                mid, mlp_w2 + (size_t)L * DIM_ * MLP_, mlp_b2 + (size_t)L * DIM_,
                x, nullptr, MROWS, DIM_, MLP_, nullptr, nullptr, nullptr);
    }
    layernorm_w<float><<<8, blk, 0, stream>>>(x, lnf_g, lnf_b, hcls, B_, SEQ_);
    gemm_f32_bias<<<dim3((NCLS_ + BN - 1) / BN, 1), blk, 0, stream>>>(
        hcls, fc_w, fc_b, out, B_, NCLS_, DIM_);
}